// Round 1
// baseline (1348.440 us; speedup 1.0000x reference)
//
#include <hip/hip_runtime.h>
#include <hip/hip_bf16.h>
#include <math.h>

// Problem constants
#define BB 16
#define NN 3136
#define CC 384
#define HDS 8
#define DHH 48
#define AGG 49
#define HI 56
#define WI 56
#define OUTD 1000
#define SCALE_F 0.14433756729740643f  // 48^-0.5

// ---------------------------------------------------------------------------
// GEMM: Y(M x NCOL) = X(M x 384) @ W(384 x NCOL), fp32, 64x64 tiles, BK=16
// ---------------------------------------------------------------------------
template <int NCOL>
__global__ __launch_bounds__(256) void gemm_xw(const float* __restrict__ X,
                                               const float* __restrict__ W,
                                               float* __restrict__ Y) {
  __shared__ __align__(16) float As[16][68];  // transposed: As[k][m]
  __shared__ __align__(16) float Bs[16][68];
  const int tid = threadIdx.x;
  const int row0 = blockIdx.x * 64;
  const int col0 = blockIdx.y * 64;
  const int tx = tid & 15, ty = tid >> 4;
  float acc[4][4];
#pragma unroll
  for (int i = 0; i < 4; i++)
#pragma unroll
    for (int j = 0; j < 4; j++) acc[i][j] = 0.f;

  for (int k0 = 0; k0 < 384; k0 += 16) {
#pragma unroll
    for (int i = 0; i < 4; i++) {
      int r = (tid >> 4) + i * 16;
      int kk = tid & 15;
      As[kk][r] = X[(size_t)(row0 + r) * 384 + k0 + kk];
    }
#pragma unroll
    for (int i = 0; i < 4; i++) {
      int r = (tid >> 6) + i * 4;
      int cc = tid & 63;
      Bs[r][cc] = W[(size_t)(k0 + r) * NCOL + col0 + cc];
    }
    __syncthreads();
#pragma unroll
    for (int kk = 0; kk < 16; kk++) {
      float4 a4 = *(const float4*)&As[kk][ty * 4];
      float4 b4 = *(const float4*)&Bs[kk][tx * 4];
      float av[4] = {a4.x, a4.y, a4.z, a4.w};
      float bv[4] = {b4.x, b4.y, b4.z, b4.w};
#pragma unroll
      for (int i = 0; i < 4; i++)
#pragma unroll
        for (int j = 0; j < 4; j++) acc[i][j] += av[i] * bv[j];
    }
    __syncthreads();
  }
#pragma unroll
  for (int i = 0; i < 4; i++) {
    int r = row0 + ty * 4 + i;
#pragma unroll
    for (int j = 0; j < 4; j++) {
      Y[(size_t)r * NCOL + col0 + tx * 4 + j] = acc[i][j];
    }
  }
}

// ---------------------------------------------------------------------------
// Pool x over 8x8 blocks -> pooled_x (B, 49, 384)
// ---------------------------------------------------------------------------
__global__ __launch_bounds__(384) void pool_x_kernel(const float* __restrict__ x,
                                                     float* __restrict__ px) {
  int blk = blockIdx.x;  // b*49 + a
  int b = blk / AGG, a = blk % AGG;
  int p1 = a / 7, p2 = a % 7;
  int c = threadIdx.x;
  float s = 0.f;
#pragma unroll
  for (int i = 0; i < 8; i++)
#pragma unroll
    for (int j = 0; j < 8; j++) {
      int n = (p1 * 8 + i) * WI + (p2 * 8 + j);
      s += x[((size_t)b * NN + n) * CC + c];
    }
  px[(size_t)blk * CC + c] = s * (1.f / 64.f);
}

// ---------------------------------------------------------------------------
// agent (B,49,384) = pooled_x @ Wq
// ---------------------------------------------------------------------------
__global__ __launch_bounds__(384) void agent_gemm_kernel(const float* __restrict__ px,
                                                         const float* __restrict__ Wq,
                                                         float* __restrict__ ag) {
  __shared__ float xr[CC];
  int blk = blockIdx.x;
  int c = threadIdx.x;
  xr[c] = px[(size_t)blk * CC + c];
  __syncthreads();
  float s = 0.f;
  for (int k = 0; k < CC; k++) s += xr[k] * Wq[(size_t)k * CC + c];
  ag[(size_t)blk * CC + c] = s;
}

// ---------------------------------------------------------------------------
// Agent attention, partial pass over token chunks (no max-sub: scores tiny).
// grid: (b,h,ch) with ch in [0,7), 448 tokens per chunk (7 tiles of 64)
// outputs: pl[z][49] = partial sum(exp), pacc[z][49*48] = partial sum(exp*v)
// ---------------------------------------------------------------------------
__global__ __launch_bounds__(256) void agent_attn_partial(
    const float* __restrict__ ag, const float* __restrict__ kv,
    const float* __restrict__ an_bias, const float* __restrict__ ah_bias,
    const float* __restrict__ aw_bias, float* __restrict__ pl,
    float* __restrict__ pacc) {
  int z = blockIdx.x;
  int ch = z % 7;
  int h = (z / 7) % HDS;
  int b = z / (7 * HDS);
  int tid = threadIdx.x;

  __shared__ __align__(16) float aL[AGG * 48];   // 2352
  __shared__ float kL[64 * 49];                  // 3136
  __shared__ float vL[64 * 49];                  // 3136
  __shared__ float pL[AGG * 65];                 // 3185

  for (int idx = tid; idx < AGG * 48; idx += 256) {
    int a = idx / 48, d = idx % 48;
    aL[idx] = ag[((size_t)b * AGG + a) * CC + h * 48 + d];
  }
  float lacc = 0.f;
  float vacc[10];
#pragma unroll
  for (int i = 0; i < 10; i++) vacc[i] = 0.f;

  for (int t0 = 0; t0 < 7; t0++) {
    int nbase = ch * 448 + t0 * 64;
    __syncthreads();
    for (int idx = tid; idx < 64 * 48; idx += 256) {
      int t = idx / 48, d = idx % 48;
      size_t src = ((size_t)b * NN + nbase + t) * 768 + h * 48 + d;
      kL[t * 49 + d] = kv[src];
      vL[t * 49 + d] = kv[src + 384];
    }
    __syncthreads();

    // scores: thread handles token t = tid&63, agents a = g, g+4, ...
    {
      int t = tid & 63;
      int g = tid >> 6;
      float kr[48];
#pragma unroll
      for (int d = 0; d < 48; d++) kr[d] = kL[t * 49 + d];
      int n = nbase + t;
      int r = n / WI, ccol = n % WI;
      for (int a = g; a < AGG; a += 4) {
        const float* ap = &aL[a * 48];
        float s = 0.f;
#pragma unroll
        for (int d = 0; d < 48; d++) s += kr[d] * ap[d];
        s = s * SCALE_F + an_bias[((size_t)h * AGG + a) * NN + n] +
            ah_bias[(h * AGG + a) * HI + r] + aw_bias[(h * AGG + a) * WI + ccol];
        pL[a * 65 + t] = __expf(s);
      }
    }
    __syncthreads();

    // l partial
    if (tid < AGG) {
      float s = 0.f;
#pragma unroll
      for (int t2 = 0; t2 < 64; t2++) s += pL[tid * 65 + t2];
      lacc += s;
    }
    // pv partial: pairs (a,d)
#pragma unroll
    for (int i = 0; i < 10; i++) {
      int pair = tid + i * 256;
      if (pair < AGG * 48) {
        int a = pair / 48, d = pair % 48;
        float s = 0.f;
#pragma unroll
        for (int t2 = 0; t2 < 64; t2++) s += pL[a * 65 + t2] * vL[t2 * 49 + d];
        vacc[i] += s;
      }
    }
  }

  if (tid < AGG) pl[(size_t)z * AGG + tid] = lacc;
#pragma unroll
  for (int i = 0; i < 10; i++) {
    int pair = tid + i * 256;
    if (pair < AGG * 48) pacc[(size_t)z * (AGG * 48) + pair] = vacc[i];
  }
}

// ---------------------------------------------------------------------------
// Merge partials -> agent_v (B,H,49,48)
// ---------------------------------------------------------------------------
__global__ __launch_bounds__(64) void agent_merge(const float* __restrict__ pl,
                                                  const float* __restrict__ pacc,
                                                  float* __restrict__ av) {
  int blk = blockIdx.x;      // (b*8+h)*49 + a
  int a = blk % AGG;
  int bh = blk / AGG;
  int d = threadIdx.x;
  float l = 0.f;
  for (int ch = 0; ch < 7; ch++) l += pl[((size_t)bh * 7 + ch) * AGG + a];
  if (d < 48) {
    float s = 0.f;
    for (int ch = 0; ch < 7; ch++)
      s += pacc[((size_t)bh * 7 + ch) * (AGG * 48) + a * 48 + d];
    av[(size_t)blk * 48 + d] = s / l;
  }
}

// ---------------------------------------------------------------------------
// q-attention + token-mean accumulation.
// grid: (b,h,chunk) chunk of 256 tokens; accumulates sum over n of out rows
// into acc(B,384) via per-block reduction + atomicAdd.
// ---------------------------------------------------------------------------
__global__ __launch_bounds__(256) void q_attn_kernel(
    const float* __restrict__ q, const float* __restrict__ ag,
    const float* __restrict__ av, const float* __restrict__ na_bias,
    const float* __restrict__ ha_bias, const float* __restrict__ wa_bias,
    float* __restrict__ acc) {
  int z = blockIdx.x;
  int chunk = z % 13;
  int h = (z / 13) % HDS;
  int b = z / (13 * HDS);
  int tid = threadIdx.x;

  __shared__ __align__(16) float smem[256 * 49];  // 50176 B
  float* aL = smem;           // 2352
  float* avL = smem + 2352;   // 2352

  for (int idx = tid; idx < AGG * 48; idx += 256) {
    int a = idx / 48, d = idx % 48;
    aL[idx] = ag[((size_t)b * AGG + a) * CC + h * 48 + d];
    avL[idx] = av[((size_t)(b * HDS + h) * AGG + a) * 48 + d];
  }
  __syncthreads();

  int n = chunk * 256 + tid;
  float orow[48];
#pragma unroll
  for (int d = 0; d < 48; d++) orow[d] = 0.f;

  if (n < NN) {
    float qr[48];
    const float* qp = &q[((size_t)b * NN + n) * CC + h * 48];
#pragma unroll
    for (int d4 = 0; d4 < 12; d4++) {
      float4 t4 = *(const float4*)&qp[d4 * 4];
      qr[d4 * 4 + 0] = t4.x;
      qr[d4 * 4 + 1] = t4.y;
      qr[d4 * 4 + 2] = t4.z;
      qr[d4 * 4 + 3] = t4.w;
    }
    int r = n / WI, ccol = n % WI;
    float p[49];
    float lsum = 0.f;
    for (int a = 0; a < AGG; a++) {
      const float* ap = &aL[a * 48];
      float s = 0.f;
#pragma unroll
      for (int d = 0; d < 48; d++) s += qr[d] * ap[d];
      s = s * SCALE_F + na_bias[((size_t)h * AGG + a) * NN + n] +
          ha_bias[(h * HI + r) * AGG + a] + wa_bias[(h * WI + ccol) * AGG + a];
      float e = __expf(s);
      p[a] = e;
      lsum += e;
    }
    float inv = 1.f / lsum;
    for (int a = 0; a < AGG; a++) {
      float pa = p[a] * inv;
      const float* vp = &avL[a * 48];
#pragma unroll
      for (int d = 0; d < 48; d++) orow[d] += pa * vp[d];
    }
  }

  __syncthreads();  // done reading aL/avL; reuse smem as oL[256][49]
  float* oL = smem;
#pragma unroll
  for (int d = 0; d < 48; d++) oL[tid * 49 + d] = orow[d];
  __syncthreads();
  if (tid < 48) {
    float s = 0.f;
    for (int t = 0; t < 256; t++) s += oL[t * 49 + tid];
    atomicAdd(&acc[(size_t)b * CC + h * 48 + tid], s);
  }
}

// ---------------------------------------------------------------------------
// Depthwise 3x3 conv on v, accumulate sum over pixels into acc(B,384)
// grid: (b,row)
// ---------------------------------------------------------------------------
__global__ __launch_bounds__(384) void dwc_kernel(const float* __restrict__ kv,
                                                  const float* __restrict__ w,
                                                  float* __restrict__ acc) {
  int z = blockIdx.x;
  int r = z % HI;
  int b = z / HI;
  int c = threadIdx.x;
  float wt[9];
#pragma unroll
  for (int i = 0; i < 9; i++) wt[i] = w[c * 9 + i];
  float s = 0.f;
  for (int ww = 0; ww < WI; ww++) {
#pragma unroll
    for (int i = 0; i < 3; i++) {
      int rr = r + i - 1;
      if (rr < 0 || rr >= HI) continue;
#pragma unroll
      for (int j = 0; j < 3; j++) {
        int cc2 = ww + j - 1;
        if (cc2 < 0 || cc2 >= WI) continue;
        s += wt[i * 3 + j] * kv[((size_t)b * NN + rr * WI + cc2) * 768 + 384 + c];
      }
    }
  }
  atomicAdd(&acc[(size_t)b * CC + c], s);
}

// ---------------------------------------------------------------------------
// Final head: pooled = acc/N + dwc_b; proj; LN; GELU-MLP; out (16,1000)
// grid: 16 blocks x 384 threads
// ---------------------------------------------------------------------------
__global__ __launch_bounds__(384) void final_kernel(
    const float* __restrict__ acc, const float* __restrict__ dwc_b,
    const float* __restrict__ Wproj, const float* __restrict__ bproj,
    const float* __restrict__ ln_g, const float* __restrict__ ln_b,
    const float* __restrict__ W1, const float* __restrict__ b1,
    const float* __restrict__ W2, const float* __restrict__ b2,
    float* __restrict__ out) {
  int b = blockIdx.x;
  int tid = threadIdx.x;
  __shared__ float pre[CC], h0[CC], h1[2 * CC];
  __shared__ float red[8];

  pre[tid] = acc[(size_t)b * CC + tid] * (1.f / (float)NN) + dwc_b[tid];
  __syncthreads();

  float pj = 0.f;
  for (int k = 0; k < CC; k++) pj += pre[k] * Wproj[(size_t)k * CC + tid];
  pj += bproj[tid];

  // LN mean
  float m;
  {
    float s = pj;
#pragma unroll
    for (int o = 32; o > 0; o >>= 1) s += __shfl_down(s, o);
    if ((tid & 63) == 0) red[tid >> 6] = s;
    __syncthreads();
    if (tid == 0) {
      float t = 0.f;
      for (int i = 0; i < 6; i++) t += red[i];
      red[6] = t * (1.f / (float)CC);
    }
    __syncthreads();
    m = red[6];
  }
  float dv = pj - m;
  __syncthreads();
  float var;
  {
    float s = dv * dv;
#pragma unroll
    for (int o = 32; o > 0; o >>= 1) s += __shfl_down(s, o);
    if ((tid & 63) == 0) red[tid >> 6] = s;
    __syncthreads();
    if (tid == 0) {
      float t = 0.f;
      for (int i = 0; i < 6; i++) t += red[i];
      red[7] = t * (1.f / (float)CC);
    }
    __syncthreads();
    var = red[7];
  }
  h0[tid] = dv * rsqrtf(var + 1e-5f) * ln_g[tid] + ln_b[tid];
  __syncthreads();

  for (int o = tid; o < 2 * CC; o += 384) {
    float s = 0.f;
    for (int k = 0; k < CC; k++) s += h0[k] * W1[(size_t)k * (2 * CC) + o];
    s += b1[o];
    h1[o] = 0.5f * s * (1.f + erff(s * 0.70710678118654752f));
  }
  __syncthreads();

  for (int o = tid; o < OUTD; o += 384) {
    float s = 0.f;
    for (int k = 0; k < 2 * CC; k++) s += h1[k] * W2[(size_t)k * OUTD + o];
    out[(size_t)b * OUTD + o] = s + b2[o];
  }
}

// ---------------------------------------------------------------------------
extern "C" void kernel_launch(void* const* d_in, const int* in_sizes, int n_in,
                              void* d_out, int out_size, void* d_ws,
                              size_t ws_size, hipStream_t stream) {
  const float* x = (const float*)d_in[0];
  const float* Wq = (const float*)d_in[1];
  const float* Wkv = (const float*)d_in[2];
  const float* an_bias = (const float*)d_in[3];
  const float* na_bias = (const float*)d_in[4];
  const float* ah_bias = (const float*)d_in[5];
  const float* aw_bias = (const float*)d_in[6];
  const float* ha_bias = (const float*)d_in[7];
  const float* wa_bias = (const float*)d_in[8];
  const float* dwc_w = (const float*)d_in[9];
  const float* dwc_b = (const float*)d_in[10];
  const float* Wproj = (const float*)d_in[11];
  const float* bproj = (const float*)d_in[12];
  const float* ln_g = (const float*)d_in[13];
  const float* ln_b = (const float*)d_in[14];
  const float* W1 = (const float*)d_in[15];
  const float* b1 = (const float*)d_in[16];
  const float* W2 = (const float*)d_in[17];
  const float* b2 = (const float*)d_in[18];
  float* out = (float*)d_out;

  const size_t M = (size_t)BB * NN;  // 50176
  float* q = (float*)d_ws;
  float* kvb = q + M * CC;                         // M*768
  float* px = kvb + M * 768;                       // 784*384
  float* agb = px + (size_t)784 * CC;              // 784*384
  float* pl = agb + (size_t)784 * CC;              // 896*49
  float* pacc = pl + (size_t)896 * AGG;            // 896*2352
  float* av = pacc + (size_t)896 * (AGG * 48);     // 6272*48
  float* accb = av + (size_t)6272 * 48;            // 16*384

  hipMemsetAsync(accb, 0, (size_t)BB * CC * sizeof(float), stream);

  dim3 blk256(256);
  hipLaunchKernelGGL((gemm_xw<384>), dim3(784, 6), blk256, 0, stream, x, Wq, q);
  hipLaunchKernelGGL((gemm_xw<768>), dim3(784, 12), blk256, 0, stream, x, Wkv, kvb);
  hipLaunchKernelGGL(pool_x_kernel, dim3(BB * AGG), dim3(384), 0, stream, x, px);
  hipLaunchKernelGGL(agent_gemm_kernel, dim3(BB * AGG), dim3(384), 0, stream, px, Wq, agb);
  hipLaunchKernelGGL(agent_attn_partial, dim3(BB * HDS * 7), blk256, 0, stream,
                     agb, kvb, an_bias, ah_bias, aw_bias, pl, pacc);
  hipLaunchKernelGGL(agent_merge, dim3(BB * HDS * AGG), dim3(64), 0, stream, pl, pacc, av);
  hipLaunchKernelGGL(q_attn_kernel, dim3(BB * HDS * 13), blk256, 0, stream, q,
                     agb, av, na_bias, ha_bias, wa_bias, accb);
  hipLaunchKernelGGL(dwc_kernel, dim3(BB * HI), dim3(384), 0, stream, kvb, dwc_w, accb);
  hipLaunchKernelGGL(final_kernel, dim3(BB), dim3(384), 0, stream, accb, dwc_b,
                     Wproj, bproj, ln_g, ln_b, W1, b1, W2, b2, out);
}

// Round 2
// 819.655 us; speedup vs baseline: 1.6451x; 1.6451x over previous
//
#include <hip/hip_runtime.h>
#include <hip/hip_bf16.h>
#include <math.h>

// Problem constants
#define BB 16
#define NN 3136
#define CC 384
#define HDS 8
#define DHH 48
#define AGG 49
#define HI 56
#define WI 56
#define OUTD 1000
#define SCALE_F 0.14433756729740643f  // 48^-0.5
#define QKVC 1152                     // q|k|v column stride

typedef __attribute__((ext_vector_type(8))) short short8;
typedef __attribute__((ext_vector_type(4))) float f32x4;

__device__ __forceinline__ float bf2f(unsigned short u) {
  union { unsigned u32; float f; } x;
  x.u32 = ((unsigned)u) << 16;
  return x.f;
}
__device__ __forceinline__ unsigned short f2bf(float f) {
  union { float f; unsigned u; } x;
  x.f = f;
  unsigned u = x.u;
  unsigned r = (u + 0x7fffu + ((u >> 16) & 1u)) >> 16;
  return (unsigned short)r;
}

// ---------------------------------------------------------------------------
// x (fp32) -> xb (bf16), 8 elems/thread
// ---------------------------------------------------------------------------
__global__ __launch_bounds__(256) void x_to_bf16(const float* __restrict__ x,
                                                 unsigned short* __restrict__ xb) {
  size_t i = ((size_t)blockIdx.x * 256 + threadIdx.x) * 8;
  float4 a = *(const float4*)(x + i);
  float4 b = *(const float4*)(x + i + 4);
  short8 o;
  o[0] = (short)f2bf(a.x); o[1] = (short)f2bf(a.y);
  o[2] = (short)f2bf(a.z); o[3] = (short)f2bf(a.w);
  o[4] = (short)f2bf(b.x); o[5] = (short)f2bf(b.y);
  o[6] = (short)f2bf(b.z); o[7] = (short)f2bf(b.w);
  *(short8*)(xb + i) = o;
}

// ---------------------------------------------------------------------------
// Build Wt (bf16, [1152][384]) = [Wq | Wkv]^T via LDS transpose
// grid (6, 18): 64x64 tiles of (k, n)
// ---------------------------------------------------------------------------
__global__ __launch_bounds__(256) void prep_wt(const float* __restrict__ Wq,
                                               const float* __restrict__ Wkv,
                                               unsigned short* __restrict__ Wt) {
  __shared__ float t[64][65];
  int k0 = blockIdx.x * 64, n0 = blockIdx.y * 64;
  const float* src;
  int ncol, nloc;
  if (n0 < 384) { src = Wq; ncol = 384; nloc = n0; }
  else          { src = Wkv; ncol = 768; nloc = n0 - 384; }
  int rr = threadIdx.x >> 6;   // 0..3
  int c = threadIdx.x & 63;
#pragma unroll
  for (int it = 0; it < 16; it++) {
    int r = it * 4 + rr;
    t[r][c] = src[(size_t)(k0 + r) * ncol + nloc + c];
  }
  __syncthreads();
#pragma unroll
  for (int it = 0; it < 16; it++) {
    int n = it * 4 + rr;  // local col -> Wt row
    Wt[(size_t)(n0 + n) * 384 + k0 + c] = f2bf(t[c][n]);
  }
}

// ---------------------------------------------------------------------------
// MFMA GEMM: qkv(bf16, [50176][1152]) = xb([50176][384]) @ Wt^T
// 128x128 tile, BK=64, 4 waves (2x2 of 64x64), double-buffered LDS,
// XOR chunk-swizzle on both write and read.
// ---------------------------------------------------------------------------
__global__ __launch_bounds__(256) void gemm_qkv(const unsigned short* __restrict__ X,
                                                const unsigned short* __restrict__ Wt,
                                                unsigned short* __restrict__ Y) {
  __shared__ __align__(16) unsigned char lds[2][2][16384];  // [dbuf][A/B][128 rows][128 B]
  const int tid = threadIdx.x;
  const int lane = tid & 63;
  const int wave = tid >> 6;
  const int wm = (wave >> 1) * 64;
  const int wn = (wave & 1) * 64;
  const int row0 = blockIdx.x * 128;
  const int col0 = blockIdx.y * 128;

  const int srow = tid >> 1;   // 0..127
  const int shalf = tid & 1;   // 0..1  (chunks 0-3 or 4-7)

  f32x4 acc[4][4];
#pragma unroll
  for (int i = 0; i < 4; i++)
#pragma unroll
    for (int j = 0; j < 4; j++) acc[i][j] = (f32x4)0.f;

  uint4 rA[4], rB[4];

  auto loadRegs = [&](int kt) {
    const unsigned short* pa = X + (size_t)(row0 + srow) * 384 + kt * 64 + shalf * 32;
    const unsigned short* pb = Wt + (size_t)(col0 + srow) * 384 + kt * 64 + shalf * 32;
#pragma unroll
    for (int c = 0; c < 4; c++) {
      rA[c] = *(const uint4*)(pa + c * 8);
      rB[c] = *(const uint4*)(pb + c * 8);
    }
  };
  auto writeLds = [&](int buf) {
    int rb = srow * 128;
    int sw = srow & 7;
#pragma unroll
    for (int c = 0; c < 4; c++) {
      int ch = (shalf * 4 + c) ^ sw;
      *(uint4*)&lds[buf][0][rb + ch * 16] = rA[c];
      *(uint4*)&lds[buf][1][rb + ch * 16] = rB[c];
    }
  };
  auto compute = [&](int buf) {
#pragma unroll
    for (int kb = 0; kb < 2; kb++) {
      int kb8 = kb * 4;
      short8 af[4], bfr[4];
#pragma unroll
      for (int i = 0; i < 4; i++) {
        int r = wm + i * 16 + (lane & 15);
        int ch = (kb8 + (lane >> 4)) ^ (r & 7);
        af[i] = *(const short8*)&lds[buf][0][r * 128 + ch * 16];
      }
#pragma unroll
      for (int j = 0; j < 4; j++) {
        int r = wn + j * 16 + (lane & 15);
        int ch = (kb8 + (lane >> 4)) ^ (r & 7);
        bfr[j] = *(const short8*)&lds[buf][1][r * 128 + ch * 16];
      }
#pragma unroll
      for (int i = 0; i < 4; i++)
#pragma unroll
        for (int j = 0; j < 4; j++)
          acc[i][j] = __builtin_amdgcn_mfma_f32_16x16x32_bf16(af[i], bfr[j], acc[i][j], 0, 0, 0);
    }
  };

  loadRegs(0);
  writeLds(0);
  __syncthreads();
  for (int kt = 0; kt < 6; kt++) {
    if (kt < 5) loadRegs(kt + 1);
    compute(kt & 1);
    __syncthreads();
    if (kt < 5) {
      writeLds((kt + 1) & 1);
      __syncthreads();
    }
  }

  // Epilogue: C/D layout col=lane&15, row=(lane>>4)*4+reg
#pragma unroll
  for (int i = 0; i < 4; i++) {
#pragma unroll
    for (int j = 0; j < 4; j++) {
      int col = col0 + wn + j * 16 + (lane & 15);
#pragma unroll
      for (int r = 0; r < 4; r++) {
        int row = row0 + wm + i * 16 + (lane >> 4) * 4 + r;
        Y[(size_t)row * QKVC + col] = f2bf(acc[i][j][r]);
      }
    }
  }
}

// ---------------------------------------------------------------------------
// Pool x over 8x8 blocks -> pooled_x (B, 49, 384)
// ---------------------------------------------------------------------------
__global__ __launch_bounds__(384) void pool_x_kernel(const float* __restrict__ x,
                                                     float* __restrict__ px) {
  int blk = blockIdx.x;  // b*49 + a
  int b = blk / AGG, a = blk % AGG;
  int p1 = a / 7, p2 = a % 7;
  int c = threadIdx.x;
  float s = 0.f;
#pragma unroll
  for (int i = 0; i < 8; i++)
#pragma unroll
    for (int j = 0; j < 8; j++) {
      int n = (p1 * 8 + i) * WI + (p2 * 8 + j);
      s += x[((size_t)b * NN + n) * CC + c];
    }
  px[(size_t)blk * CC + c] = s * (1.f / 64.f);
}

// ---------------------------------------------------------------------------
// agent (B,49,384) = pooled_x @ Wq   (fp32)
// ---------------------------------------------------------------------------
__global__ __launch_bounds__(384) void agent_gemm_kernel(const float* __restrict__ px,
                                                         const float* __restrict__ Wq,
                                                         float* __restrict__ ag) {
  __shared__ float xr[CC];
  int blk = blockIdx.x;
  int c = threadIdx.x;
  xr[c] = px[(size_t)blk * CC + c];
  __syncthreads();
  float s = 0.f;
  for (int k = 0; k < CC; k++) s += xr[k] * Wq[(size_t)k * CC + c];
  ag[(size_t)blk * CC + c] = s;
}

// ---------------------------------------------------------------------------
// Agent attention partials over token chunks (no max-sub: scores tiny).
// grid: (b,h,ch), ch in [0,7): 448 tokens each. Vectorized LDS (float4).
// ---------------------------------------------------------------------------
__global__ __launch_bounds__(256) void agent_attn_partial(
    const float* __restrict__ ag, const unsigned short* __restrict__ qkv,
    const float* __restrict__ an_bias, const float* __restrict__ ah_bias,
    const float* __restrict__ aw_bias, float* __restrict__ pl,
    float* __restrict__ pacc) {
  int z = blockIdx.x;
  int ch = z % 7;
  int h = (z / 7) % HDS;
  int b = z / (7 * HDS);
  int tid = threadIdx.x;

  __shared__ __align__(16) float aL[AGG * 48];  // 9408 B
  __shared__ __align__(16) float kL[64 * 52];   // 13312 B
  __shared__ __align__(16) float vT[48 * 68];   // 13056 B (vT[d][t])
  __shared__ __align__(16) float pL[AGG * 68];  // 13328 B

  for (int idx = tid; idx < AGG * 48; idx += 256) {
    int a = idx / 48, d = idx % 48;
    aL[idx] = ag[((size_t)b * AGG + a) * CC + h * 48 + d];
  }
  float lacc = 0.f;
  float vacc[10];
#pragma unroll
  for (int i = 0; i < 10; i++) vacc[i] = 0.f;

  for (int t0 = 0; t0 < 7; t0++) {
    int nbase = ch * 448 + t0 * 64;
    __syncthreads();
    // stage k -> kL[t][d], v -> vT[d][t]  (bf16 -> f32)
    for (int idx = tid; idx < 768; idx += 256) {
      int m2 = idx / 384;          // 0:k 1:v
      int rem = idx % 384;
      int t = rem / 6, c8 = rem % 6;
      size_t src = ((size_t)b * NN + nbase + t) * QKVC + (m2 ? 768 : 384) + h * 48 + c8 * 8;
      short8 s8 = *(const short8*)&qkv[src];
      if (m2 == 0) {
#pragma unroll
        for (int e = 0; e < 8; e++) kL[t * 52 + c8 * 8 + e] = bf2f((unsigned short)s8[e]);
      } else {
#pragma unroll
        for (int e = 0; e < 8; e++) vT[(c8 * 8 + e) * 68 + t] = bf2f((unsigned short)s8[e]);
      }
    }
    __syncthreads();

    // scores: thread -> token t = tid&63, agents a = g, g+4, ...
    {
      int t = tid & 63;
      int g = tid >> 6;
      float4 kr[12];
#pragma unroll
      for (int c = 0; c < 12; c++) kr[c] = *(const float4*)&kL[t * 52 + c * 4];
      int n = nbase + t;
      int r = n / WI, ccol = n % WI;
      for (int a = g; a < AGG; a += 4) {
        const float4* ap = (const float4*)&aL[a * 48];
        float s = 0.f;
#pragma unroll
        for (int c = 0; c < 12; c++) {
          float4 a4 = ap[c];
          s += kr[c].x * a4.x + kr[c].y * a4.y + kr[c].z * a4.z + kr[c].w * a4.w;
        }
        s = s * SCALE_F + an_bias[((size_t)h * AGG + a) * NN + n] +
            ah_bias[(h * AGG + a) * HI + r] + aw_bias[(h * AGG + a) * WI + ccol];
        pL[a * 68 + t] = __expf(s);
      }
    }
    __syncthreads();

    // l partial
    if (tid < AGG) {
      float s = 0.f;
#pragma unroll
      for (int t4 = 0; t4 < 16; t4++) {
        float4 p4 = *(const float4*)&pL[tid * 68 + t4 * 4];
        s += p4.x + p4.y + p4.z + p4.w;
      }
      lacc += s;
    }
    // pv partial
#pragma unroll
    for (int i = 0; i < 10; i++) {
      int pair = tid + i * 256;
      if (pair < AGG * 48) {
        int a = pair / 48, d = pair % 48;
        const float* pr = &pL[a * 68];
        const float* vr = &vT[d * 68];
        float s = 0.f;
#pragma unroll
        for (int t4 = 0; t4 < 16; t4++) {
          float4 p4 = *(const float4*)&pr[t4 * 4];
          float4 v4 = *(const float4*)&vr[t4 * 4];
          s += p4.x * v4.x + p4.y * v4.y + p4.z * v4.z + p4.w * v4.w;
        }
        vacc[i] += s;
      }
    }
  }

  if (tid < AGG) pl[(size_t)z * AGG + tid] = lacc;
#pragma unroll
  for (int i = 0; i < 10; i++) {
    int pair = tid + i * 256;
    if (pair < AGG * 48) pacc[(size_t)z * (AGG * 48) + pair] = vacc[i];
  }
}

// ---------------------------------------------------------------------------
// Merge partials -> agent_v (B,H,49,48)
// ---------------------------------------------------------------------------
__global__ __launch_bounds__(64) void agent_merge(const float* __restrict__ pl,
                                                  const float* __restrict__ pacc,
                                                  float* __restrict__ av) {
  int blk = blockIdx.x;  // (b*8+h)*49 + a
  int a = blk % AGG;
  int bh = blk / AGG;
  int d = threadIdx.x;
  float l = 0.f;
  for (int ch = 0; ch < 7; ch++) l += pl[((size_t)bh * 7 + ch) * AGG + a];
  if (d < 48) {
    float s = 0.f;
    for (int ch = 0; ch < 7; ch++)
      s += pacc[((size_t)bh * 7 + ch) * (AGG * 48) + a * 48 + d];
    av[(size_t)blk * 48 + d] = s / l;
  }
}

// ---------------------------------------------------------------------------
// q-attention (single-pass softmax) + token-mean accumulation into acc(B,384)
// ---------------------------------------------------------------------------
__global__ __launch_bounds__(256) void q_attn_kernel(
    const unsigned short* __restrict__ qkv, const float* __restrict__ ag,
    const float* __restrict__ av, const float* __restrict__ na_bias,
    const float* __restrict__ ha_bias, const float* __restrict__ wa_bias,
    float* __restrict__ acc) {
  int z = blockIdx.x;
  int chunk = z % 13;
  int h = (z / 13) % HDS;
  int b = z / (13 * HDS);
  int tid = threadIdx.x;

  __shared__ __align__(16) float smem[256 * 49];  // 50176 B
  float* aL = smem;          // 2352
  float* avL = smem + 2352;  // 2352

  for (int idx = tid; idx < AGG * 48; idx += 256) {
    int a = idx / 48, d = idx % 48;
    aL[idx] = ag[((size_t)b * AGG + a) * CC + h * 48 + d];
    avL[idx] = av[((size_t)(b * HDS + h) * AGG + a) * 48 + d];
  }
  __syncthreads();

  int n = chunk * 256 + tid;
  float orow[48];
#pragma unroll
  for (int d = 0; d < 48; d++) orow[d] = 0.f;

  if (n < NN) {
    float qr[48];
    const unsigned short* qp = qkv + ((size_t)b * NN + n) * QKVC + h * 48;
#pragma unroll
    for (int c8 = 0; c8 < 6; c8++) {
      short8 v8 = *(const short8*)&qp[c8 * 8];
#pragma unroll
      for (int e = 0; e < 8; e++) qr[c8 * 8 + e] = bf2f((unsigned short)v8[e]);
    }
    int r = n / WI, ccol = n % WI;
    float lsum = 0.f;
    for (int a = 0; a < AGG; a++) {
      const float4* ap = (const float4*)&aL[a * 48];
      float s = 0.f;
#pragma unroll
      for (int c = 0; c < 12; c++) {
        float4 a4 = ap[c];
        s += qr[c * 4 + 0] * a4.x + qr[c * 4 + 1] * a4.y + qr[c * 4 + 2] * a4.z +
             qr[c * 4 + 3] * a4.w;
      }
      s = s * SCALE_F + na_bias[((size_t)h * AGG + a) * NN + n] +
          ha_bias[(h * HI + r) * AGG + a] + wa_bias[(h * WI + ccol) * AGG + a];
      float e = __expf(s);
      lsum += e;
      const float4* vp = (const float4*)&avL[a * 48];
#pragma unroll
      for (int c = 0; c < 12; c++) {
        float4 v4 = vp[c];
        orow[c * 4 + 0] += e * v4.x;
        orow[c * 4 + 1] += e * v4.y;
        orow[c * 4 + 2] += e * v4.z;
        orow[c * 4 + 3] += e * v4.w;
      }
    }
    float inv = 1.f / lsum;
#pragma unroll
    for (int d = 0; d < 48; d++) orow[d] *= inv;
  }

  __syncthreads();  // done with aL/avL; reuse smem as oL[256][49]
  float* oL = smem;
#pragma unroll
  for (int d = 0; d < 48; d++) oL[tid * 49 + d] = orow[d];
  __syncthreads();
  if (tid < 48) {
    float s = 0.f;
    for (int t = 0; t < 256; t++) s += oL[t * 49 + tid];
    atomicAdd(&acc[(size_t)b * CC + h * 48 + tid], s);
  }
}

// ---------------------------------------------------------------------------
// Depthwise 3x3 conv on v (bf16 in qkv), accumulate pixel-sum into acc(B,384)
// ---------------------------------------------------------------------------
__global__ __launch_bounds__(384) void dwc_kernel(const unsigned short* __restrict__ qkv,
                                                  const float* __restrict__ w,
                                                  float* __restrict__ acc) {
  int z = blockIdx.x;
  int r = z % HI;
  int b = z / HI;
  int c = threadIdx.x;
  float wt[9];
#pragma unroll
  for (int i = 0; i < 9; i++) wt[i] = w[c * 9 + i];
  float s = 0.f;
  for (int ww = 0; ww < WI; ww++) {
#pragma unroll
    for (int i = 0; i < 3; i++) {
      int rr = r + i - 1;
      if (rr < 0 || rr >= HI) continue;
#pragma unroll
      for (int j = 0; j < 3; j++) {
        int cc2 = ww + j - 1;
        if (cc2 < 0 || cc2 >= WI) continue;
        s += wt[i * 3 + j] * bf2f(qkv[((size_t)b * NN + rr * WI + cc2) * QKVC + 768 + c]);
      }
    }
  }
  atomicAdd(&acc[(size_t)b * CC + c], s);
}

// ---------------------------------------------------------------------------
// Final head: pooled = acc/N + dwc_b; proj; LN; GELU-MLP; out (16,1000)
// ---------------------------------------------------------------------------
__global__ __launch_bounds__(384) void final_kernel(
    const float* __restrict__ acc, const float* __restrict__ dwc_b,
    const float* __restrict__ Wproj, const float* __restrict__ bproj,
    const float* __restrict__ ln_g, const float* __restrict__ ln_b,
    const float* __restrict__ W1, const float* __restrict__ b1,
    const float* __restrict__ W2, const float* __restrict__ b2,
    float* __restrict__ out) {
  int b = blockIdx.x;
  int tid = threadIdx.x;
  __shared__ float pre[CC], h0[CC], h1[2 * CC];
  __shared__ float red[8];

  pre[tid] = acc[(size_t)b * CC + tid] * (1.f / (float)NN) + dwc_b[tid];
  __syncthreads();

  float pj = 0.f;
  for (int k = 0; k < CC; k++) pj += pre[k] * Wproj[(size_t)k * CC + tid];
  pj += bproj[tid];

  float m;
  {
    float s = pj;
#pragma unroll
    for (int o = 32; o > 0; o >>= 1) s += __shfl_down(s, o);
    if ((tid & 63) == 0) red[tid >> 6] = s;
    __syncthreads();
    if (tid == 0) {
      float t = 0.f;
      for (int i = 0; i < 6; i++) t += red[i];
      red[6] = t * (1.f / (float)CC);
    }
    __syncthreads();
    m = red[6];
  }
  float dv = pj - m;
  __syncthreads();
  float var;
  {
    float s = dv * dv;
#pragma unroll
    for (int o = 32; o > 0; o >>= 1) s += __shfl_down(s, o);
    if ((tid & 63) == 0) red[tid >> 6] = s;
    __syncthreads();
    if (tid == 0) {
      float t = 0.f;
      for (int i = 0; i < 6; i++) t += red[i];
      red[7] = t * (1.f / (float)CC);
    }
    __syncthreads();
    var = red[7];
  }
  h0[tid] = dv * rsqrtf(var + 1e-5f) * ln_g[tid] + ln_b[tid];
  __syncthreads();

  for (int o = tid; o < 2 * CC; o += 384) {
    float s = 0.f;
    for (int k = 0; k < CC; k++) s += h0[k] * W1[(size_t)k * (2 * CC) + o];
    s += b1[o];
    h1[o] = 0.5f * s * (1.f + erff(s * 0.70710678118654752f));
  }
  __syncthreads();

  for (int o = tid; o < OUTD; o += 384) {
    float s = 0.f;
    for (int k = 0; k < 2 * CC; k++) s += h1[k] * W2[(size_t)k * OUTD + o];
    out[(size_t)b * OUTD + o] = s + b2[o];
  }
}

// ---------------------------------------------------------------------------
extern "C" void kernel_launch(void* const* d_in, const int* in_sizes, int n_in,
                              void* d_out, int out_size, void* d_ws,
                              size_t ws_size, hipStream_t stream) {
  const float* x = (const float*)d_in[0];
  const float* Wq = (const float*)d_in[1];
  const float* Wkv = (const float*)d_in[2];
  const float* an_bias = (const float*)d_in[3];
  const float* na_bias = (const float*)d_in[4];
  const float* ah_bias = (const float*)d_in[5];
  const float* aw_bias = (const float*)d_in[6];
  const float* ha_bias = (const float*)d_in[7];
  const float* wa_bias = (const float*)d_in[8];
  const float* dwc_w = (const float*)d_in[9];
  const float* dwc_b = (const float*)d_in[10];
  const float* Wproj = (const float*)d_in[11];
  const float* bproj = (const float*)d_in[12];
  const float* ln_g = (const float*)d_in[13];
  const float* ln_b = (const float*)d_in[14];
  const float* W1 = (const float*)d_in[15];
  const float* b1 = (const float*)d_in[16];
  const float* W2 = (const float*)d_in[17];
  const float* b2 = (const float*)d_in[18];
  float* out = (float*)d_out;

  const size_t M = (size_t)BB * NN;  // 50176
  char* wsp = (char*)d_ws;
  unsigned short* xb = (unsigned short*)wsp;            wsp += M * CC * 2;            // 38.5 MB
  unsigned short* Wtb = (unsigned short*)wsp;           wsp += (size_t)QKVC * CC * 2; // 0.88 MB
  unsigned short* qkv = (unsigned short*)wsp;           wsp += M * QKVC * 2;          // 115.6 MB
  float* px = (float*)wsp;                              wsp += (size_t)784 * CC * 4;
  float* agb = (float*)wsp;                             wsp += (size_t)784 * CC * 4;
  float* pl = (float*)wsp;                              wsp += (size_t)896 * AGG * 4;
  float* pacc = (float*)wsp;                            wsp += (size_t)896 * AGG * 48 * 4;
  float* av = (float*)wsp;                              wsp += (size_t)6272 * 48 * 4;
  float* accb = (float*)wsp;                            wsp += (size_t)BB * CC * 4;

  hipMemsetAsync(accb, 0, (size_t)BB * CC * sizeof(float), stream);

  dim3 blk256(256);
  hipLaunchKernelGGL(x_to_bf16, dim3((unsigned)(M * CC / 8 / 256)), blk256, 0, stream, x, xb);
  hipLaunchKernelGGL(prep_wt, dim3(6, 18), blk256, 0, stream, Wq, Wkv, Wtb);
  hipLaunchKernelGGL(gemm_qkv, dim3(392, 9), blk256, 0, stream, xb, Wtb, qkv);
  hipLaunchKernelGGL(pool_x_kernel, dim3(BB * AGG), dim3(384), 0, stream, x, px);
  hipLaunchKernelGGL(agent_gemm_kernel, dim3(BB * AGG), dim3(384), 0, stream, px, Wq, agb);
  hipLaunchKernelGGL(agent_attn_partial, dim3(BB * HDS * 7), blk256, 0, stream,
                     agb, qkv, an_bias, ah_bias, aw_bias, pl, pacc);
  hipLaunchKernelGGL(agent_merge, dim3(BB * HDS * AGG), dim3(64), 0, stream, pl, pacc, av);
  hipLaunchKernelGGL(q_attn_kernel, dim3(BB * HDS * 13), blk256, 0, stream, qkv,
                     agb, av, na_bias, ha_bias, wa_bias, accb);
  hipLaunchKernelGGL(dwc_kernel, dim3(BB * HI), dim3(384), 0, stream, qkv, dwc_w, accb);
  hipLaunchKernelGGL(final_kernel, dim3(BB), dim3(384), 0, stream, accb, dwc_b,
                     Wproj, bproj, ln_g, ln_b, W1, b1, W2, b2, out);
}

// Round 3
// 691.214 us; speedup vs baseline: 1.9508x; 1.1858x over previous
//
#include <hip/hip_runtime.h>
#include <hip/hip_bf16.h>
#include <math.h>

// Problem constants
#define BB 16
#define NN 3136
#define CC 384
#define HDS 8
#define DHH 48
#define AGG 49
#define HI 56
#define WI 56
#define OUTD 1000
#define SCALE_F 0.14433756729740643f  // 48^-0.5
#define QKVC 1152                     // q|k|v column stride

typedef __attribute__((ext_vector_type(8))) short short8;
typedef __attribute__((ext_vector_type(4))) float f32x4;

__device__ __forceinline__ float bf2f(unsigned short u) {
  union { unsigned u32; float f; } x;
  x.u32 = ((unsigned)u) << 16;
  return x.f;
}
__device__ __forceinline__ unsigned short f2bf(float f) {
  union { float f; unsigned u; } x;
  x.f = f;
  unsigned u = x.u;
  unsigned r = (u + 0x7fffu + ((u >> 16) & 1u)) >> 16;
  return (unsigned short)r;
}

// ---------------------------------------------------------------------------
// x (fp32) -> xb (bf16), 8 elems/thread
// ---------------------------------------------------------------------------
__global__ __launch_bounds__(256) void x_to_bf16(const float* __restrict__ x,
                                                 unsigned short* __restrict__ xb) {
  size_t i = ((size_t)blockIdx.x * 256 + threadIdx.x) * 8;
  float4 a = *(const float4*)(x + i);
  float4 b = *(const float4*)(x + i + 4);
  short8 o;
  o[0] = (short)f2bf(a.x); o[1] = (short)f2bf(a.y);
  o[2] = (short)f2bf(a.z); o[3] = (short)f2bf(a.w);
  o[4] = (short)f2bf(b.x); o[5] = (short)f2bf(b.y);
  o[6] = (short)f2bf(b.z); o[7] = (short)f2bf(b.w);
  *(short8*)(xb + i) = o;
}

// ---------------------------------------------------------------------------
// Build Wt (bf16, [1152][384]) = [Wq | Wkv]^T via LDS transpose
// ---------------------------------------------------------------------------
__global__ __launch_bounds__(256) void prep_wt(const float* __restrict__ Wq,
                                               const float* __restrict__ Wkv,
                                               unsigned short* __restrict__ Wt) {
  __shared__ float t[64][65];
  int k0 = blockIdx.x * 64, n0 = blockIdx.y * 64;
  const float* src;
  int ncol, nloc;
  if (n0 < 384) { src = Wq; ncol = 384; nloc = n0; }
  else          { src = Wkv; ncol = 768; nloc = n0 - 384; }
  int rr = threadIdx.x >> 6;
  int c = threadIdx.x & 63;
#pragma unroll
  for (int it = 0; it < 16; it++) {
    int r = it * 4 + rr;
    t[r][c] = src[(size_t)(k0 + r) * ncol + nloc + c];
  }
  __syncthreads();
#pragma unroll
  for (int it = 0; it < 16; it++) {
    int n = it * 4 + rr;
    Wt[(size_t)(n0 + n) * 384 + k0 + c] = f2bf(t[c][n]);
  }
}

// ---------------------------------------------------------------------------
// MFMA GEMM: qkv(bf16, [50176][1152]) = xb @ Wt^T. 128x128 tile, BK=64.
// ---------------------------------------------------------------------------
__global__ __launch_bounds__(256) void gemm_qkv(const unsigned short* __restrict__ X,
                                                const unsigned short* __restrict__ Wt,
                                                unsigned short* __restrict__ Y) {
  __shared__ __align__(16) unsigned char lds[2][2][16384];
  const int tid = threadIdx.x;
  const int lane = tid & 63;
  const int wave = tid >> 6;
  const int wm = (wave >> 1) * 64;
  const int wn = (wave & 1) * 64;
  const int row0 = blockIdx.x * 128;
  const int col0 = blockIdx.y * 128;
  const int srow = tid >> 1;
  const int shalf = tid & 1;

  f32x4 acc[4][4];
#pragma unroll
  for (int i = 0; i < 4; i++)
#pragma unroll
    for (int j = 0; j < 4; j++) acc[i][j] = (f32x4)0.f;

  uint4 rA[4], rB[4];

  auto loadRegs = [&](int kt) {
    const unsigned short* pa = X + (size_t)(row0 + srow) * 384 + kt * 64 + shalf * 32;
    const unsigned short* pb = Wt + (size_t)(col0 + srow) * 384 + kt * 64 + shalf * 32;
#pragma unroll
    for (int c = 0; c < 4; c++) {
      rA[c] = *(const uint4*)(pa + c * 8);
      rB[c] = *(const uint4*)(pb + c * 8);
    }
  };
  auto writeLds = [&](int buf) {
    int rb = srow * 128;
    int sw = srow & 7;
#pragma unroll
    for (int c = 0; c < 4; c++) {
      int chn = (shalf * 4 + c) ^ sw;
      *(uint4*)&lds[buf][0][rb + chn * 16] = rA[c];
      *(uint4*)&lds[buf][1][rb + chn * 16] = rB[c];
    }
  };
  auto compute = [&](int buf) {
#pragma unroll
    for (int kb = 0; kb < 2; kb++) {
      int kb8 = kb * 4;
      short8 af[4], bfr[4];
#pragma unroll
      for (int i = 0; i < 4; i++) {
        int r = wm + i * 16 + (lane & 15);
        int chn = (kb8 + (lane >> 4)) ^ (r & 7);
        af[i] = *(const short8*)&lds[buf][0][r * 128 + chn * 16];
      }
#pragma unroll
      for (int j = 0; j < 4; j++) {
        int r = wn + j * 16 + (lane & 15);
        int chn = (kb8 + (lane >> 4)) ^ (r & 7);
        bfr[j] = *(const short8*)&lds[buf][1][r * 128 + chn * 16];
      }
#pragma unroll
      for (int i = 0; i < 4; i++)
#pragma unroll
        for (int j = 0; j < 4; j++)
          acc[i][j] = __builtin_amdgcn_mfma_f32_16x16x32_bf16(af[i], bfr[j], acc[i][j], 0, 0, 0);
    }
  };

  loadRegs(0);
  writeLds(0);
  __syncthreads();
  for (int kt = 0; kt < 6; kt++) {
    if (kt < 5) loadRegs(kt + 1);
    compute(kt & 1);
    __syncthreads();
    if (kt < 5) {
      writeLds((kt + 1) & 1);
      __syncthreads();
    }
  }

#pragma unroll
  for (int i = 0; i < 4; i++) {
#pragma unroll
    for (int j = 0; j < 4; j++) {
      int col = col0 + wn + j * 16 + (lane & 15);
#pragma unroll
      for (int r = 0; r < 4; r++) {
        int row = row0 + wm + i * 16 + (lane >> 4) * 4 + r;
        Y[(size_t)row * QKVC + col] = f2bf(acc[i][j][r]);
      }
    }
  }
}

// ---------------------------------------------------------------------------
// Combined bias precompute: cb1[h][a][n] (q-side), cb2[h][a][n] (agent-side)
// ---------------------------------------------------------------------------
__global__ __launch_bounds__(256) void make_cbias(
    const float* __restrict__ na, const float* __restrict__ ha,
    const float* __restrict__ wa, const float* __restrict__ an,
    const float* __restrict__ ah, const float* __restrict__ aw,
    float* __restrict__ cb1, float* __restrict__ cb2) {
  int ha_idx = blockIdx.x;  // h*49 + a
  int h = ha_idx / AGG, a = ha_idx % AGG;
  for (int n = threadIdx.x; n < NN; n += 256) {
    int r = n / WI, c = n % WI;
    size_t base = (size_t)ha_idx * NN + n;
    cb1[base] = na[base] + ha[(h * HI + r) * AGG + a] + wa[(h * WI + c) * AGG + a];
    cb2[base] = an[base] + ah[(size_t)ha_idx * HI + r] + aw[(size_t)ha_idx * WI + c];
  }
}

// ---------------------------------------------------------------------------
// Pool x over 8x8 blocks -> pooled_x (B, 49, 384)
// ---------------------------------------------------------------------------
__global__ __launch_bounds__(384) void pool_x_kernel(const float* __restrict__ x,
                                                     float* __restrict__ px) {
  int blk = blockIdx.x;
  int b = blk / AGG, a = blk % AGG;
  int p1 = a / 7, p2 = a % 7;
  int c = threadIdx.x;
  float s = 0.f;
#pragma unroll
  for (int i = 0; i < 8; i++)
#pragma unroll
    for (int j = 0; j < 8; j++) {
      int n = (p1 * 8 + i) * WI + (p2 * 8 + j);
      s += x[((size_t)b * NN + n) * CC + c];
    }
  px[(size_t)blk * CC + c] = s * (1.f / 64.f);
}

// ---------------------------------------------------------------------------
// agent (B,49,384) = pooled_x @ Wq   (fp32)
// ---------------------------------------------------------------------------
__global__ __launch_bounds__(384) void agent_gemm_kernel(const float* __restrict__ px,
                                                         const float* __restrict__ Wq,
                                                         float* __restrict__ ag) {
  __shared__ float xr[CC];
  int blk = blockIdx.x;
  int c = threadIdx.x;
  xr[c] = px[(size_t)blk * CC + c];
  __syncthreads();
  float s = 0.f;
  for (int k = 0; k < CC; k++) s += xr[k] * Wq[(size_t)k * CC + c];
  ag[(size_t)blk * CC + c] = s;
}

// ---------------------------------------------------------------------------
// Agent attention partials, MFMA. grid (b,h,ch): 25 chunks of 128 tokens.
// 128 threads = 2 waves; each wave: 64 tokens x 64 agents (49 valid).
// ---------------------------------------------------------------------------
__global__ __launch_bounds__(128) void agent_attn_mfma(
    const unsigned short* __restrict__ qkv, const float* __restrict__ agb,
    const float* __restrict__ cb2, float* __restrict__ pl,
    float* __restrict__ pacc) {
  int z = blockIdx.x;
  int ch = z % 25;
  int h = (z / 25) % HDS;
  int b = z / (25 * HDS);
  int tid = threadIdx.x;
  int lane = tid & 63;
  int wv = tid >> 6;
  int lo = lane & 15, g = lane >> 4;

  __shared__ __align__(16) unsigned short aT[64 * 72];   // [a][d] 9216 B
  __shared__ __align__(16) unsigned short vT[48 * 136];  // [d][t] 13056 B
  __shared__ __align__(16) unsigned short pT[2][64 * 72];// per-wave [a][t]
  __shared__ float ldsAV[AGG * 48];                      // 9408 B
  __shared__ float ldsL[52];

  // zero
  for (int i = tid; i < (64 * 72) / 2; i += 128) ((unsigned*)aT)[i] = 0;
  for (int i = tid; i < AGG * 48; i += 128) ldsAV[i] = 0.f;
  if (tid < 52) ldsL[tid] = 0.f;
  __syncthreads();
  // fill aT
  for (int idx = tid; idx < AGG * 48; idx += 128) {
    int a = idx / 48, d = idx % 48;
    aT[a * 72 + d] = f2bf(agb[((size_t)b * AGG + a) * CC + h * 48 + d]);
  }
  // stage vT[d][t] for 128 tokens (clamped)
  for (int idx = tid; idx < 128 * 6; idx += 128) {
    int t = idx / 6, c8 = idx % 6;
    int n = ch * 128 + t;
    int nc = n < NN ? n : NN - 1;
    short8 s8 = *(const short8*)&qkv[((size_t)b * NN + nc) * QKVC + 768 + h * 48 + c8 * 8];
#pragma unroll
    for (int e = 0; e < 8; e++) vT[(c8 * 8 + e) * 136 + t] = (unsigned short)s8[e];
  }
  __syncthreads();

  // ---- QK^T ----
  short8 af0[4], af1[4], kf0[4], kf1[4];
#pragma unroll
  for (int mt = 0; mt < 4; mt++) {
    const unsigned short* p = &aT[(mt * 16 + lo) * 72 + g * 8];
    af0[mt] = *(const short8*)p;
    af1[mt] = *(const short8*)(p + 32);
  }
  int nbase = ch * 128 + wv * 64;
#pragma unroll
  for (int nt = 0; nt < 4; nt++) {
    int n = nbase + nt * 16 + lo;
    int nc = n < NN ? n : NN - 1;
    const unsigned short* kp = qkv + ((size_t)b * NN + nc) * QKVC + 384 + h * 48;
    kf0[nt] = *(const short8*)(kp + g * 8);
    if (g < 2) kf1[nt] = *(const short8*)(kp + 32 + g * 8);
    else { short8 zz = {0, 0, 0, 0, 0, 0, 0, 0}; kf1[nt] = zz; }
  }
  f32x4 acc[4][4];
#pragma unroll
  for (int mt = 0; mt < 4; mt++)
#pragma unroll
    for (int nt = 0; nt < 4; nt++) acc[mt][nt] = (f32x4)0.f;
#pragma unroll
  for (int mt = 0; mt < 4; mt++)
#pragma unroll
    for (int nt = 0; nt < 4; nt++) {
      acc[mt][nt] = __builtin_amdgcn_mfma_f32_16x16x32_bf16(af0[mt], kf0[nt], acc[mt][nt], 0, 0, 0);
      acc[mt][nt] = __builtin_amdgcn_mfma_f32_16x16x32_bf16(af1[mt], kf1[nt], acc[mt][nt], 0, 0, 0);
    }

  // ---- bias + exp (invalid -> 0) ----
#pragma unroll
  for (int mt = 0; mt < 4; mt++)
#pragma unroll
    for (int nt = 0; nt < 4; nt++)
#pragma unroll
      for (int r = 0; r < 4; r++) {
        int a = mt * 16 + g * 4 + r;
        int n = nbase + nt * 16 + lo;
        float e = 0.f;
        if (a < AGG && n < NN)
          e = __expf(acc[mt][nt][r] * SCALE_F + cb2[((size_t)h * AGG + a) * NN + n]);
        acc[mt][nt][r] = e;
      }

  // ---- l partials (row-sum over tokens) ----
#pragma unroll
  for (int mt = 0; mt < 4; mt++)
#pragma unroll
    for (int r = 0; r < 4; r++) {
      float s = acc[mt][0][r] + acc[mt][1][r] + acc[mt][2][r] + acc[mt][3][r];
      s += __shfl_xor(s, 1); s += __shfl_xor(s, 2);
      s += __shfl_xor(s, 4); s += __shfl_xor(s, 8);
      if (lo == 0) {
        int a = mt * 16 + g * 4 + r;
        if (a < AGG) atomicAdd(&ldsL[a], s);
      }
    }

  // ---- write P to pT[a][t] (bf16) ----
#pragma unroll
  for (int mt = 0; mt < 4; mt++)
#pragma unroll
    for (int nt = 0; nt < 4; nt++)
#pragma unroll
      for (int r = 0; r < 4; r++) {
        int a = mt * 16 + g * 4 + r;
        int t = nt * 16 + lo;
        pT[wv][a * 72 + t] = f2bf(acc[mt][nt][r]);
      }

  // ---- PV: AV_p = P @ V ----
  short8 pa0[4], pa1[4], vb0[3], vb1[3];
#pragma unroll
  for (int mt = 0; mt < 4; mt++) {
    const unsigned short* p = &pT[wv][(mt * 16 + lo) * 72 + g * 8];
    pa0[mt] = *(const short8*)p;
    pa1[mt] = *(const short8*)(p + 32);
  }
#pragma unroll
  for (int ntd = 0; ntd < 3; ntd++) {
    const unsigned short* p = &vT[(ntd * 16 + lo) * 136 + wv * 64 + g * 8];
    vb0[ntd] = *(const short8*)p;
    vb1[ntd] = *(const short8*)(p + 32);
  }
  f32x4 acc2[4][3];
#pragma unroll
  for (int mt = 0; mt < 4; mt++)
#pragma unroll
    for (int ntd = 0; ntd < 3; ntd++) acc2[mt][ntd] = (f32x4)0.f;
#pragma unroll
  for (int mt = 0; mt < 4; mt++)
#pragma unroll
    for (int ntd = 0; ntd < 3; ntd++) {
      acc2[mt][ntd] = __builtin_amdgcn_mfma_f32_16x16x32_bf16(pa0[mt], vb0[ntd], acc2[mt][ntd], 0, 0, 0);
      acc2[mt][ntd] = __builtin_amdgcn_mfma_f32_16x16x32_bf16(pa1[mt], vb1[ntd], acc2[mt][ntd], 0, 0, 0);
    }
#pragma unroll
  for (int mt = 0; mt < 4; mt++)
#pragma unroll
    for (int ntd = 0; ntd < 3; ntd++)
#pragma unroll
      for (int r = 0; r < 4; r++) {
        int a = mt * 16 + g * 4 + r;
        if (a < AGG) atomicAdd(&ldsAV[a * 48 + ntd * 16 + lo], acc2[mt][ntd][r]);
      }
  __syncthreads();

  for (int idx = tid; idx < AGG * 48; idx += 128) pacc[(size_t)z * (AGG * 48) + idx] = ldsAV[idx];
  if (tid < AGG) pl[(size_t)z * AGG + tid] = ldsL[tid];
}

// ---------------------------------------------------------------------------
// Merge partials -> agent_v (B,H,49,48)
// ---------------------------------------------------------------------------
__global__ __launch_bounds__(64) void agent_merge(const float* __restrict__ pl,
                                                  const float* __restrict__ pacc,
                                                  float* __restrict__ av) {
  int blk = blockIdx.x;  // (b*8+h)*49 + a
  int a = blk % AGG;
  int bh = blk / AGG;
  int d = threadIdx.x;
  float l = 0.f;
  for (int ch = 0; ch < 25; ch++) l += pl[((size_t)bh * 25 + ch) * AGG + a];
  if (d < 48) {
    float s = 0.f;
    for (int ch = 0; ch < 25; ch++)
      s += pacc[((size_t)bh * 25 + ch) * (AGG * 48) + a * 48 + d];
    av[(size_t)blk * 48 + d] = s / l;
  }
}

// ---------------------------------------------------------------------------
// q-attention MFMA + token-mean accumulation. grid (b,h,ch): 13 chunks of 256.
// 256 threads = 4 waves; each wave: 64 tokens.
// ---------------------------------------------------------------------------
__global__ __launch_bounds__(256) void q_attn_mfma(
    const unsigned short* __restrict__ qkv, const float* __restrict__ agb,
    const float* __restrict__ av, const float* __restrict__ cb1,
    float* __restrict__ accb) {
  int z = blockIdx.x;
  int ch = z % 13;
  int h = (z / 13) % HDS;
  int b = z / (13 * HDS);
  int tid = threadIdx.x;
  int lane = tid & 63;
  int wv = tid >> 6;
  int lo = lane & 15, g = lane >> 4;

  __shared__ __align__(16) unsigned short aT[64 * 72];    // [a][d]
  __shared__ __align__(16) unsigned short avT[48 * 72];   // [d][a]
  __shared__ __align__(16) unsigned short pT[4][64 * 72]; // per-wave [t][a]

  for (int i = tid; i < (64 * 72) / 2; i += 256) ((unsigned*)aT)[i] = 0;
  for (int i = tid; i < (48 * 72) / 2; i += 256) ((unsigned*)avT)[i] = 0;
  __syncthreads();
  for (int idx = tid; idx < AGG * 48; idx += 256) {
    int a = idx / 48, d = idx % 48;
    aT[a * 72 + d] = f2bf(agb[((size_t)b * AGG + a) * CC + h * 48 + d]);
    avT[d * 72 + a] = f2bf(av[(((size_t)b * HDS + h) * AGG + a) * 48 + d]);
  }
  __syncthreads();

  // ---- S^T = A @ Q^T ----
  short8 af0[4], af1[4], qf0[4], qf1[4];
#pragma unroll
  for (int mt = 0; mt < 4; mt++) {
    const unsigned short* p = &aT[(mt * 16 + lo) * 72 + g * 8];
    af0[mt] = *(const short8*)p;
    af1[mt] = *(const short8*)(p + 32);
  }
  int nbase = ch * 256 + wv * 64;
#pragma unroll
  for (int nt = 0; nt < 4; nt++) {
    int n = nbase + nt * 16 + lo;
    int nc = n < NN ? n : NN - 1;
    const unsigned short* qp = qkv + ((size_t)b * NN + nc) * QKVC + h * 48;
    qf0[nt] = *(const short8*)(qp + g * 8);
    if (g < 2) qf1[nt] = *(const short8*)(qp + 32 + g * 8);
    else { short8 zz = {0, 0, 0, 0, 0, 0, 0, 0}; qf1[nt] = zz; }
  }
  f32x4 acc[4][4];
#pragma unroll
  for (int mt = 0; mt < 4; mt++)
#pragma unroll
    for (int nt = 0; nt < 4; nt++) acc[mt][nt] = (f32x4)0.f;
#pragma unroll
  for (int mt = 0; mt < 4; mt++)
#pragma unroll
    for (int nt = 0; nt < 4; nt++) {
      acc[mt][nt] = __builtin_amdgcn_mfma_f32_16x16x32_bf16(af0[mt], qf0[nt], acc[mt][nt], 0, 0, 0);
      acc[mt][nt] = __builtin_amdgcn_mfma_f32_16x16x32_bf16(af1[mt], qf1[nt], acc[mt][nt], 0, 0, 0);
    }

  // ---- bias + exp + softmax (per token col), write normalized P^T ----
#pragma unroll
  for (int nt = 0; nt < 4; nt++) {
    int n = nbase + nt * 16 + lo;
    int nc = n < NN ? n : NN - 1;
    float lsum = 0.f;
#pragma unroll
    for (int mt = 0; mt < 4; mt++)
#pragma unroll
      for (int r = 0; r < 4; r++) {
        int a = mt * 16 + g * 4 + r;
        float e = 0.f;
        if (a < AGG)
          e = __expf(acc[mt][nt][r] * SCALE_F + cb1[((size_t)h * AGG + a) * NN + nc]);
        acc[mt][nt][r] = e;
        lsum += e;
      }
    lsum += __shfl_xor(lsum, 16);
    lsum += __shfl_xor(lsum, 32);
    float inv = 1.f / lsum;
    int t = nt * 16 + lo;
#pragma unroll
    for (int mt = 0; mt < 4; mt++)
#pragma unroll
      for (int rp = 0; rp < 2; rp++) {
        unsigned u0 = f2bf(acc[mt][nt][rp * 2] * inv);
        unsigned u1 = f2bf(acc[mt][nt][rp * 2 + 1] * inv);
        int a = mt * 16 + g * 4 + rp * 2;
        *(unsigned*)&pT[wv][t * 72 + a] = u0 | (u1 << 16);
      }
  }

  // ---- O^T = AV^T @ P^T ----
  short8 vf0[3], vf1[3], pf0[4], pf1[4];
#pragma unroll
  for (int mtd = 0; mtd < 3; mtd++) {
    const unsigned short* p = &avT[(mtd * 16 + lo) * 72 + g * 8];
    vf0[mtd] = *(const short8*)p;
    vf1[mtd] = *(const short8*)(p + 32);
  }
#pragma unroll
  for (int nt = 0; nt < 4; nt++) {
    const unsigned short* p = &pT[wv][(nt * 16 + lo) * 72 + g * 8];
    pf0[nt] = *(const short8*)p;
    pf1[nt] = *(const short8*)(p + 32);
  }
  f32x4 acc2[3][4];
#pragma unroll
  for (int mtd = 0; mtd < 3; mtd++)
#pragma unroll
    for (int nt = 0; nt < 4; nt++) acc2[mtd][nt] = (f32x4)0.f;
#pragma unroll
  for (int mtd = 0; mtd < 3; mtd++)
#pragma unroll
    for (int nt = 0; nt < 4; nt++) {
      acc2[mtd][nt] = __builtin_amdgcn_mfma_f32_16x16x32_bf16(vf0[mtd], pf0[nt], acc2[mtd][nt], 0, 0, 0);
      acc2[mtd][nt] = __builtin_amdgcn_mfma_f32_16x16x32_bf16(vf1[mtd], pf1[nt], acc2[mtd][nt], 0, 0, 0);
    }

  // ---- token-sum (valid only) -> atomicAdd acc(B,384) ----
#pragma unroll
  for (int mtd = 0; mtd < 3; mtd++)
#pragma unroll
    for (int r = 0; r < 4; r++) {
      float v = 0.f;
#pragma unroll
      for (int nt = 0; nt < 4; nt++) {
        int n = nbase + nt * 16 + lo;
        v += (n < NN) ? acc2[mtd][nt][r] : 0.f;
      }
      v += __shfl_xor(v, 1); v += __shfl_xor(v, 2);
      v += __shfl_xor(v, 4); v += __shfl_xor(v, 8);
      if (lo == 0) {
        int d = mtd * 16 + g * 4 + r;
        atomicAdd(&accb[(size_t)b * CC + h * 48 + d], v);
      }
    }
}

// ---------------------------------------------------------------------------
// Depthwise 3x3 conv on v (bf16 in qkv), accumulate pixel-sum into acc(B,384)
// ---------------------------------------------------------------------------
__global__ __launch_bounds__(384) void dwc_kernel(const unsigned short* __restrict__ qkv,
                                                  const float* __restrict__ w,
                                                  float* __restrict__ acc) {
  int z = blockIdx.x;
  int r = z % HI;
  int b = z / HI;
  int c = threadIdx.x;
  float wt[9];
#pragma unroll
  for (int i = 0; i < 9; i++) wt[i] = w[c * 9 + i];
  float s = 0.f;
  for (int ww = 0; ww < WI; ww++) {
#pragma unroll
    for (int i = 0; i < 3; i++) {
      int rr = r + i - 1;
      if (rr < 0 || rr >= HI) continue;
#pragma unroll
      for (int j = 0; j < 3; j++) {
        int cc2 = ww + j - 1;
        if (cc2 < 0 || cc2 >= WI) continue;
        s += wt[i * 3 + j] * bf2f(qkv[((size_t)b * NN + rr * WI + cc2) * QKVC + 768 + c]);
      }
    }
  }
  atomicAdd(&acc[(size_t)b * CC + c], s);
}

// ---------------------------------------------------------------------------
// Final head: pooled = acc/N + dwc_b; proj; LN; GELU-MLP; out (16,1000)
// ---------------------------------------------------------------------------
__global__ __launch_bounds__(384) void final_kernel(
    const float* __restrict__ acc, const float* __restrict__ dwc_b,
    const float* __restrict__ Wproj, const float* __restrict__ bproj,
    const float* __restrict__ ln_g, const float* __restrict__ ln_b,
    const float* __restrict__ W1, const float* __restrict__ b1,
    const float* __restrict__ W2, const float* __restrict__ b2,
    float* __restrict__ out) {
  int b = blockIdx.x;
  int tid = threadIdx.x;
  __shared__ float pre[CC], h0[CC], h1[2 * CC];
  __shared__ float red[8];

  pre[tid] = acc[(size_t)b * CC + tid] * (1.f / (float)NN) + dwc_b[tid];
  __syncthreads();

  float pj = 0.f;
  for (int k = 0; k < CC; k++) pj += pre[k] * Wproj[(size_t)k * CC + tid];
  pj += bproj[tid];

  float m;
  {
    float s = pj;
#pragma unroll
    for (int o = 32; o > 0; o >>= 1) s += __shfl_down(s, o);
    if ((tid & 63) == 0) red[tid >> 6] = s;
    __syncthreads();
    if (tid == 0) {
      float t = 0.f;
      for (int i = 0; i < 6; i++) t += red[i];
      red[6] = t * (1.f / (float)CC);
    }
    __syncthreads();
    m = red[6];
  }
  float dv = pj - m;
  __syncthreads();
  float var;
  {
    float s = dv * dv;
#pragma unroll
    for (int o = 32; o > 0; o >>= 1) s += __shfl_down(s, o);
    if ((tid & 63) == 0) red[tid >> 6] = s;
    __syncthreads();
    if (tid == 0) {
      float t = 0.f;
      for (int i = 0; i < 6; i++) t += red[i];
      red[7] = t * (1.f / (float)CC);
    }
    __syncthreads();
    var = red[7];
  }
  h0[tid] = dv * rsqrtf(var + 1e-5f) * ln_g[tid] + ln_b[tid];
  __syncthreads();

  for (int o = tid; o < 2 * CC; o += 384) {
    float s = 0.f;
    for (int k = 0; k < CC; k++) s += h0[k] * W1[(size_t)k * (2 * CC) + o];
    s += b1[o];
    h1[o] = 0.5f * s * (1.f + erff(s * 0.70710678118654752f));
  }
  __syncthreads();

  for (int o = tid; o < OUTD; o += 384) {
    float s = 0.f;
    for (int k = 0; k < 2 * CC; k++) s += h1[k] * W2[(size_t)k * OUTD + o];
    out[(size_t)b * OUTD + o] = s + b2[o];
  }
}

// ---------------------------------------------------------------------------
extern "C" void kernel_launch(void* const* d_in, const int* in_sizes, int n_in,
                              void* d_out, int out_size, void* d_ws,
                              size_t ws_size, hipStream_t stream) {
  const float* x = (const float*)d_in[0];
  const float* Wq = (const float*)d_in[1];
  const float* Wkv = (const float*)d_in[2];
  const float* an_bias = (const float*)d_in[3];
  const float* na_bias = (const float*)d_in[4];
  const float* ah_bias = (const float*)d_in[5];
  const float* aw_bias = (const float*)d_in[6];
  const float* ha_bias = (const float*)d_in[7];
  const float* wa_bias = (const float*)d_in[8];
  const float* dwc_w = (const float*)d_in[9];
  const float* dwc_b = (const float*)d_in[10];
  const float* Wproj = (const float*)d_in[11];
  const float* bproj = (const float*)d_in[12];
  const float* ln_g = (const float*)d_in[13];
  const float* ln_b = (const float*)d_in[14];
  const float* W1 = (const float*)d_in[15];
  const float* b1 = (const float*)d_in[16];
  const float* W2 = (const float*)d_in[17];
  const float* b2 = (const float*)d_in[18];
  float* out = (float*)d_out;

  const size_t M = (size_t)BB * NN;  // 50176
  char* wsp = (char*)d_ws;
  unsigned short* xb = (unsigned short*)wsp;     // 38.5 MB; reused as pacc
  float* pacc = (float*)wsp;                     wsp += M * CC * 2;
  unsigned short* Wtb = (unsigned short*)wsp;    wsp += (size_t)QKVC * CC * 2;
  unsigned short* qkv = (unsigned short*)wsp;    wsp += M * QKVC * 2;
  float* px = (float*)wsp;                       wsp += (size_t)784 * CC * 4;
  float* agb = (float*)wsp;                      wsp += (size_t)784 * CC * 4;
  float* cb1 = (float*)wsp;                      wsp += (size_t)HDS * AGG * NN * 4;
  float* cb2 = (float*)wsp;                      wsp += (size_t)HDS * AGG * NN * 4;
  float* pl = (float*)wsp;                       wsp += (size_t)3200 * AGG * 4;
  float* av = (float*)wsp;                       wsp += (size_t)6272 * 48 * 4;
  float* accb = (float*)wsp;                     wsp += (size_t)BB * CC * 4;

  hipMemsetAsync(accb, 0, (size_t)BB * CC * sizeof(float), stream);

  dim3 blk256(256);
  hipLaunchKernelGGL(x_to_bf16, dim3((unsigned)(M * CC / 8 / 256)), blk256, 0, stream, x, xb);
  hipLaunchKernelGGL(prep_wt, dim3(6, 18), blk256, 0, stream, Wq, Wkv, Wtb);
  hipLaunchKernelGGL(gemm_qkv, dim3(392, 9), blk256, 0, stream, xb, Wtb, qkv);
  hipLaunchKernelGGL(make_cbias, dim3(HDS * AGG), blk256, 0, stream, na_bias,
                     ha_bias, wa_bias, an_bias, ah_bias, aw_bias, cb1, cb2);
  hipLaunchKernelGGL(pool_x_kernel, dim3(BB * AGG), dim3(384), 0, stream, x, px);
  hipLaunchKernelGGL(agent_gemm_kernel, dim3(BB * AGG), dim3(384), 0, stream, px, Wq, agb);
  hipLaunchKernelGGL(agent_attn_mfma, dim3(BB * HDS * 25), dim3(128), 0, stream,
                     qkv, agb, cb2, pl, pacc);
  hipLaunchKernelGGL(agent_merge, dim3(BB * HDS * AGG), dim3(64), 0, stream, pl, pacc, av);
  hipLaunchKernelGGL(q_attn_mfma, dim3(BB * HDS * 13), blk256, 0, stream, qkv,
                     agb, av, cb1, accb);
  hipLaunchKernelGGL(dwc_kernel, dim3(BB * HI), dim3(384), 0, stream, qkv, dwc_w, accb);
  hipLaunchKernelGGL(final_kernel, dim3(BB), dim3(384), 0, stream, accb, dwc_b,
                     Wproj, bproj, ln_g, ln_b, W1, b1, W2, b2, out);
}

// Round 4
// 538.179 us; speedup vs baseline: 2.5056x; 1.2844x over previous
//
#include <hip/hip_runtime.h>
#include <hip/hip_bf16.h>
#include <math.h>

// Problem constants
#define BB 16
#define NN 3136
#define CC 384
#define HDS 8
#define DHH 48
#define AGG 49
#define HI 56
#define WI 56
#define OUTD 1000
#define SCALE_F 0.14433756729740643f  // 48^-0.5
#define QKVC 1152                     // q|k|v column stride

typedef __attribute__((ext_vector_type(8))) short short8;
typedef __attribute__((ext_vector_type(4))) float f32x4;

__device__ __forceinline__ float bf2f(unsigned short u) {
  union { unsigned u32; float f; } x;
  x.u32 = ((unsigned)u) << 16;
  return x.f;
}
__device__ __forceinline__ unsigned short f2bf(float f) {
  union { float f; unsigned u; } x;
  x.f = f;
  unsigned u = x.u;
  unsigned r = (u + 0x7fffu + ((u >> 16) & 1u)) >> 16;
  return (unsigned short)r;
}

// ---------------------------------------------------------------------------
// x (fp32) -> xb (bf16), 8 elems/thread
// ---------------------------------------------------------------------------
__global__ __launch_bounds__(256) void x_to_bf16(const float* __restrict__ x,
                                                 unsigned short* __restrict__ xb) {
  size_t i = ((size_t)blockIdx.x * 256 + threadIdx.x) * 8;
  float4 a = *(const float4*)(x + i);
  float4 b = *(const float4*)(x + i + 4);
  short8 o;
  o[0] = (short)f2bf(a.x); o[1] = (short)f2bf(a.y);
  o[2] = (short)f2bf(a.z); o[3] = (short)f2bf(a.w);
  o[4] = (short)f2bf(b.x); o[5] = (short)f2bf(b.y);
  o[6] = (short)f2bf(b.z); o[7] = (short)f2bf(b.w);
  *(short8*)(xb + i) = o;
}

// ---------------------------------------------------------------------------
// Build Wt (bf16, [1152][384]) = [Wq | Wkv]^T via LDS transpose
// ---------------------------------------------------------------------------
__global__ __launch_bounds__(256) void prep_wt(const float* __restrict__ Wq,
                                               const float* __restrict__ Wkv,
                                               unsigned short* __restrict__ Wt) {
  __shared__ float t[64][65];
  int k0 = blockIdx.x * 64, n0 = blockIdx.y * 64;
  const float* src;
  int ncol, nloc;
  if (n0 < 384) { src = Wq; ncol = 384; nloc = n0; }
  else          { src = Wkv; ncol = 768; nloc = n0 - 384; }
  int rr = threadIdx.x >> 6;
  int c = threadIdx.x & 63;
#pragma unroll
  for (int it = 0; it < 16; it++) {
    int r = it * 4 + rr;
    t[r][c] = src[(size_t)(k0 + r) * ncol + nloc + c];
  }
  __syncthreads();
#pragma unroll
  for (int it = 0; it < 16; it++) {
    int n = it * 4 + rr;
    Wt[(size_t)(n0 + n) * 384 + k0 + c] = f2bf(t[c][n]);
  }
}

// ---------------------------------------------------------------------------
// MFMA GEMM: qkv(bf16, [50176][1152]) = xb @ Wt^T. 128x128 tile, BK=64.
// ---------------------------------------------------------------------------
__global__ __launch_bounds__(256) void gemm_qkv(const unsigned short* __restrict__ X,
                                                const unsigned short* __restrict__ Wt,
                                                unsigned short* __restrict__ Y) {
  __shared__ __align__(16) unsigned char lds[2][2][16384];
  const int tid = threadIdx.x;
  const int lane = tid & 63;
  const int wave = tid >> 6;
  const int wm = (wave >> 1) * 64;
  const int wn = (wave & 1) * 64;
  const int row0 = blockIdx.x * 128;
  const int col0 = blockIdx.y * 128;
  const int srow = tid >> 1;
  const int shalf = tid & 1;

  f32x4 acc[4][4];
#pragma unroll
  for (int i = 0; i < 4; i++)
#pragma unroll
    for (int j = 0; j < 4; j++) acc[i][j] = (f32x4)0.f;

  uint4 rA[4], rB[4];

  auto loadRegs = [&](int kt) {
    const unsigned short* pa = X + (size_t)(row0 + srow) * 384 + kt * 64 + shalf * 32;
    const unsigned short* pb = Wt + (size_t)(col0 + srow) * 384 + kt * 64 + shalf * 32;
#pragma unroll
    for (int c = 0; c < 4; c++) {
      rA[c] = *(const uint4*)(pa + c * 8);
      rB[c] = *(const uint4*)(pb + c * 8);
    }
  };
  auto writeLds = [&](int buf) {
    int rb = srow * 128;
    int sw = srow & 7;
#pragma unroll
    for (int c = 0; c < 4; c++) {
      int chn = (shalf * 4 + c) ^ sw;
      *(uint4*)&lds[buf][0][rb + chn * 16] = rA[c];
      *(uint4*)&lds[buf][1][rb + chn * 16] = rB[c];
    }
  };
  auto compute = [&](int buf) {
#pragma unroll
    for (int kb = 0; kb < 2; kb++) {
      int kb8 = kb * 4;
      short8 af[4], bfr[4];
#pragma unroll
      for (int i = 0; i < 4; i++) {
        int r = wm + i * 16 + (lane & 15);
        int chn = (kb8 + (lane >> 4)) ^ (r & 7);
        af[i] = *(const short8*)&lds[buf][0][r * 128 + chn * 16];
      }
#pragma unroll
      for (int j = 0; j < 4; j++) {
        int r = wn + j * 16 + (lane & 15);
        int chn = (kb8 + (lane >> 4)) ^ (r & 7);
        bfr[j] = *(const short8*)&lds[buf][1][r * 128 + chn * 16];
      }
#pragma unroll
      for (int i = 0; i < 4; i++)
#pragma unroll
        for (int j = 0; j < 4; j++)
          acc[i][j] = __builtin_amdgcn_mfma_f32_16x16x32_bf16(af[i], bfr[j], acc[i][j], 0, 0, 0);
    }
  };

  loadRegs(0);
  writeLds(0);
  __syncthreads();
  for (int kt = 0; kt < 6; kt++) {
    if (kt < 5) loadRegs(kt + 1);
    compute(kt & 1);
    __syncthreads();
    if (kt < 5) {
      writeLds((kt + 1) & 1);
      __syncthreads();
    }
  }

#pragma unroll
  for (int i = 0; i < 4; i++) {
#pragma unroll
    for (int j = 0; j < 4; j++) {
      int col = col0 + wn + j * 16 + (lane & 15);
#pragma unroll
      for (int r = 0; r < 4; r++) {
        int row = row0 + wm + i * 16 + (lane >> 4) * 4 + r;
        Y[(size_t)row * QKVC + col] = f2bf(acc[i][j][r]);
      }
    }
  }
}

// ---------------------------------------------------------------------------
// Combined bias precompute: cb1[h][a][n] (q-side), cb2[h][a][n] (agent-side)
// ---------------------------------------------------------------------------
__global__ __launch_bounds__(256) void make_cbias(
    const float* __restrict__ na, const float* __restrict__ ha,
    const float* __restrict__ wa, const float* __restrict__ an,
    const float* __restrict__ ah, const float* __restrict__ aw,
    float* __restrict__ cb1, float* __restrict__ cb2) {
  int ha_idx = blockIdx.x;  // h*49 + a
  int h = ha_idx / AGG, a = ha_idx % AGG;
  for (int n = threadIdx.x; n < NN; n += 256) {
    int r = n / WI, c = n % WI;
    size_t base = (size_t)ha_idx * NN + n;
    cb1[base] = na[base] + ha[(h * HI + r) * AGG + a] + wa[(h * WI + c) * AGG + a];
    cb2[base] = an[base] + ah[(size_t)ha_idx * HI + r] + aw[(size_t)ha_idx * WI + c];
  }
}

// ---------------------------------------------------------------------------
// Pool xb over 8x8 blocks -> pooled_x (B, 49, 384) fp32
// ---------------------------------------------------------------------------
__global__ __launch_bounds__(384) void pool_x_kernel(const unsigned short* __restrict__ xb,
                                                     float* __restrict__ px) {
  int blk = blockIdx.x;
  int b = blk / AGG, a = blk % AGG;
  int p1 = a / 7, p2 = a % 7;
  int c = threadIdx.x;
  float s = 0.f;
#pragma unroll
  for (int i = 0; i < 8; i++)
#pragma unroll
    for (int j = 0; j < 8; j++) {
      int n = (p1 * 8 + i) * WI + (p2 * 8 + j);
      s += bf2f(xb[((size_t)b * NN + n) * CC + c]);
    }
  px[(size_t)blk * CC + c] = s * (1.f / 64.f);
}

// ---------------------------------------------------------------------------
// agent (B,49,384) = pooled_x @ Wq   (fp32 math, bf16 out)
// ---------------------------------------------------------------------------
__global__ __launch_bounds__(384) void agent_gemm_kernel(const float* __restrict__ px,
                                                         const float* __restrict__ Wq,
                                                         unsigned short* __restrict__ agbf) {
  __shared__ float xr[CC];
  int blk = blockIdx.x;
  int c = threadIdx.x;
  xr[c] = px[(size_t)blk * CC + c];
  __syncthreads();
  float s = 0.f;
  for (int k = 0; k < CC; k++) s += xr[k] * Wq[(size_t)k * CC + c];
  agbf[(size_t)blk * CC + c] = f2bf(s);
}

// ---------------------------------------------------------------------------
// Agent attention, persistent per (b,h,quarter). 256 thr = 4 waves.
// Each wave: 64 tokens/chunk, 4 chunks (784 tokens/quarter).
// Register-accumulated PV partials; one atomic reduce at the end.
// ---------------------------------------------------------------------------
__global__ __launch_bounds__(256) void agent_attn_v2(
    const unsigned short* __restrict__ qkv, const unsigned short* __restrict__ agbf,
    const float* __restrict__ cb2, float* __restrict__ laccg,
    float* __restrict__ avacc) {
  int z = blockIdx.x;
  int qtr = z & 3;
  int h = (z >> 2) & 7;
  int b = z >> 5;
  int tid = threadIdx.x, lane = tid & 63, wv = tid >> 6;
  int lo = lane & 15, g = lane >> 4;

  __shared__ __align__(16) unsigned short vT[4][48 * 72];  // per-wave [d][t]
  __shared__ __align__(16) unsigned short pT[4][64 * 72];  // per-wave [a][t]
  __shared__ float ldsAV[AGG * 48];
  __shared__ float ldsL[AGG];

  for (int i = tid; i < AGG * 48; i += 256) ldsAV[i] = 0.f;
  if (tid < AGG) ldsL[tid] = 0.f;
  __syncthreads();

  // agent A-fragments (rows=a, k=d), loaded once from global
  short8 af0[4], af1[4];
#pragma unroll
  for (int mt = 0; mt < 4; mt++) {
    int a = mt * 16 + lo;
    int ac = a < AGG ? a : AGG - 1;
    const unsigned short* p = agbf + ((size_t)b * AGG + ac) * CC + h * 48;
    af0[mt] = *(const short8*)(p + g * 8);
    if (g < 2) af1[mt] = *(const short8*)(p + 32 + g * 8);
    else { short8 zz = {0, 0, 0, 0, 0, 0, 0, 0}; af1[mt] = zz; }
  }

  f32x4 acc2[4][3];
#pragma unroll
  for (int mt = 0; mt < 4; mt++)
#pragma unroll
    for (int ntd = 0; ntd < 3; ntd++) acc2[mt][ntd] = (f32x4)0.f;
  float laccR[4][4];
#pragma unroll
  for (int mt = 0; mt < 4; mt++)
#pragma unroll
    for (int r = 0; r < 4; r++) laccR[mt][r] = 0.f;

  const int tok0 = qtr * 784;
  for (int ci = 0; ci < 4; ci++) {
    const int vcnt = (ci < 3) ? 256 : 16;
    const int tb = tok0 + ci * 256;
    const int wb = tb + wv * 64;

    // stage this wave's V^T tile (64 tokens)
    {
      int t = lane;
      int n = wb + t;
      int nc = n < NN ? n : NN - 1;
      const unsigned short* vp = qkv + ((size_t)b * NN + nc) * QKVC + 768 + h * 48;
#pragma unroll
      for (int c8 = 0; c8 < 6; c8++) {
        short8 s8 = *(const short8*)(vp + c8 * 8);
#pragma unroll
        for (int e = 0; e < 8; e++) vT[wv][(c8 * 8 + e) * 72 + t] = (unsigned short)s8[e];
      }
    }

    // K-fragments (B-op: col=token, k=d)
    short8 kf0[4], kf1[4];
#pragma unroll
    for (int nt = 0; nt < 4; nt++) {
      int n = wb + nt * 16 + lo;
      int nc = n < NN ? n : NN - 1;
      const unsigned short* kp = qkv + ((size_t)b * NN + nc) * QKVC + 384 + h * 48;
      kf0[nt] = *(const short8*)(kp + g * 8);
      if (g < 2) kf1[nt] = *(const short8*)(kp + 32 + g * 8);
      else { short8 zz = {0, 0, 0, 0, 0, 0, 0, 0}; kf1[nt] = zz; }
    }

    f32x4 acc[4][4];
#pragma unroll
    for (int mt = 0; mt < 4; mt++)
#pragma unroll
      for (int nt = 0; nt < 4; nt++) acc[mt][nt] = (f32x4)0.f;
#pragma unroll
    for (int mt = 0; mt < 4; mt++)
#pragma unroll
      for (int nt = 0; nt < 4; nt++) {
        acc[mt][nt] = __builtin_amdgcn_mfma_f32_16x16x32_bf16(af0[mt], kf0[nt], acc[mt][nt], 0, 0, 0);
        acc[mt][nt] = __builtin_amdgcn_mfma_f32_16x16x32_bf16(af1[mt], kf1[nt], acc[mt][nt], 0, 0, 0);
      }

    // bias + exp (invalid -> 0)
#pragma unroll
    for (int mt = 0; mt < 4; mt++)
#pragma unroll
      for (int nt = 0; nt < 4; nt++)
#pragma unroll
        for (int r = 0; r < 4; r++) {
          int a = mt * 16 + g * 4 + r;
          int tl = wv * 64 + nt * 16 + lo;
          float e = 0.f;
          if (a < AGG && tl < vcnt)
            e = __expf(acc[mt][nt][r] * SCALE_F + cb2[((size_t)h * AGG + a) * NN + tb + tl]);
          acc[mt][nt][r] = e;
        }

    // l partials (registers, defer reduce)
#pragma unroll
    for (int mt = 0; mt < 4; mt++)
#pragma unroll
      for (int r = 0; r < 4; r++)
        laccR[mt][r] += acc[mt][0][r] + acc[mt][1][r] + acc[mt][2][r] + acc[mt][3][r];

    // write P -> pT[wv][a][t]
#pragma unroll
    for (int mt = 0; mt < 4; mt++)
#pragma unroll
      for (int nt = 0; nt < 4; nt++)
#pragma unroll
        for (int r = 0; r < 4; r++) {
          int a = mt * 16 + g * 4 + r;
          int t = nt * 16 + lo;
          pT[wv][a * 72 + t] = f2bf(acc[mt][nt][r]);
        }

    // PV accumulate into registers (K = tokens)
    short8 pa0[4], pa1[4], vb0[3], vb1[3];
#pragma unroll
    for (int mt = 0; mt < 4; mt++) {
      const unsigned short* p = &pT[wv][(mt * 16 + lo) * 72 + g * 8];
      pa0[mt] = *(const short8*)p;
      pa1[mt] = *(const short8*)(p + 32);
    }
#pragma unroll
    for (int ntd = 0; ntd < 3; ntd++) {
      const unsigned short* p = &vT[wv][(ntd * 16 + lo) * 72 + g * 8];
      vb0[ntd] = *(const short8*)p;
      vb1[ntd] = *(const short8*)(p + 32);
    }
#pragma unroll
    for (int mt = 0; mt < 4; mt++)
#pragma unroll
      for (int ntd = 0; ntd < 3; ntd++) {
        acc2[mt][ntd] = __builtin_amdgcn_mfma_f32_16x16x32_bf16(pa0[mt], vb0[ntd], acc2[mt][ntd], 0, 0, 0);
        acc2[mt][ntd] = __builtin_amdgcn_mfma_f32_16x16x32_bf16(pa1[mt], vb1[ntd], acc2[mt][ntd], 0, 0, 0);
      }
  }

  // reduce l across lanes, once
#pragma unroll
  for (int mt = 0; mt < 4; mt++)
#pragma unroll
    for (int r = 0; r < 4; r++) {
      float s = laccR[mt][r];
      s += __shfl_xor(s, 1); s += __shfl_xor(s, 2);
      s += __shfl_xor(s, 4); s += __shfl_xor(s, 8);
      if (lo == 0) {
        int a = mt * 16 + g * 4 + r;
        if (a < AGG) atomicAdd(&ldsL[a], s);
      }
    }
  // reduce AV partials, once
#pragma unroll
  for (int mt = 0; mt < 4; mt++)
#pragma unroll
    for (int ntd = 0; ntd < 3; ntd++)
#pragma unroll
      for (int r = 0; r < 4; r++) {
        int a = mt * 16 + g * 4 + r;
        if (a < AGG) atomicAdd(&ldsAV[a * 48 + ntd * 16 + lo], acc2[mt][ntd][r]);
      }
  __syncthreads();
  size_t obase = ((size_t)b * HDS + h) * AGG;
  for (int i = tid; i < AGG * 48; i += 256) atomicAdd(&avacc[obase * 48 + i], ldsAV[i]);
  if (tid < AGG) atomicAdd(&laccg[obase + tid], ldsL[tid]);
}

// ---------------------------------------------------------------------------
// Normalize: av = avacc / l
// ---------------------------------------------------------------------------
__global__ __launch_bounds__(64) void av_normalize(const float* __restrict__ laccg,
                                                   const float* __restrict__ avacc,
                                                   float* __restrict__ av) {
  int blk = blockIdx.x;  // bh*49 + a
  int d = threadIdx.x;
  if (d < 48) av[(size_t)blk * 48 + d] = avacc[(size_t)blk * 48 + d] / laccg[blk];
}

// ---------------------------------------------------------------------------
// q-attention, persistent per (b,h,quarter). acc2 accumulated across chunks
// (invalid tokens zeroed via inv=0); one atomic reduce at the end.
// ---------------------------------------------------------------------------
__global__ __launch_bounds__(256) void q_attn_v2(
    const unsigned short* __restrict__ qkv, const unsigned short* __restrict__ agbf,
    const float* __restrict__ av, const float* __restrict__ cb1,
    float* __restrict__ accb) {
  int z = blockIdx.x;
  int qtr = z & 3;
  int h = (z >> 2) & 7;
  int b = z >> 5;
  int tid = threadIdx.x, lane = tid & 63, wv = tid >> 6;
  int lo = lane & 15, g = lane >> 4;

  __shared__ __align__(16) unsigned short avT[48 * 72];    // [d][a], zero-padded a
  __shared__ __align__(16) unsigned short pT[4][64 * 72];  // per-wave [t][a]

  for (int i = tid; i < (48 * 72) / 2; i += 256) ((unsigned*)avT)[i] = 0;
  __syncthreads();
  for (int idx = tid; idx < AGG * 48; idx += 256) {
    int a = idx / 48, d = idx % 48;
    avT[d * 72 + a] = f2bf(av[(((size_t)b * HDS + h) * AGG + a) * 48 + d]);
  }
  __syncthreads();

  // agent A-frags once
  short8 af0[4], af1[4];
#pragma unroll
  for (int mt = 0; mt < 4; mt++) {
    int a = mt * 16 + lo;
    int ac = a < AGG ? a : AGG - 1;
    const unsigned short* p = agbf + ((size_t)b * AGG + ac) * CC + h * 48;
    af0[mt] = *(const short8*)(p + g * 8);
    if (g < 2) af1[mt] = *(const short8*)(p + 32 + g * 8);
    else { short8 zz = {0, 0, 0, 0, 0, 0, 0, 0}; af1[mt] = zz; }
  }
  // AV^T frags once (k=a dim zero-padded in avT)
  short8 vf0[3], vf1[3];
#pragma unroll
  for (int mtd = 0; mtd < 3; mtd++) {
    const unsigned short* p = &avT[(mtd * 16 + lo) * 72 + g * 8];
    vf0[mtd] = *(const short8*)p;
    vf1[mtd] = *(const short8*)(p + 32);
  }

  f32x4 acc2[3][4];
#pragma unroll
  for (int mtd = 0; mtd < 3; mtd++)
#pragma unroll
    for (int nt = 0; nt < 4; nt++) acc2[mtd][nt] = (f32x4)0.f;

  const int tok0 = qtr * 784;
  for (int ci = 0; ci < 4; ci++) {
    const int vcnt = (ci < 3) ? 256 : 16;
    const int tb = tok0 + ci * 256;
    const int wb = tb + wv * 64;

    short8 qf0[4], qf1[4];
#pragma unroll
    for (int nt = 0; nt < 4; nt++) {
      int n = wb + nt * 16 + lo;
      int nc = n < NN ? n : NN - 1;
      const unsigned short* qp = qkv + ((size_t)b * NN + nc) * QKVC + h * 48;
      qf0[nt] = *(const short8*)(qp + g * 8);
      if (g < 2) qf1[nt] = *(const short8*)(qp + 32 + g * 8);
      else { short8 zz = {0, 0, 0, 0, 0, 0, 0, 0}; qf1[nt] = zz; }
    }
    f32x4 acc[4][4];
#pragma unroll
    for (int mt = 0; mt < 4; mt++)
#pragma unroll
      for (int nt = 0; nt < 4; nt++) acc[mt][nt] = (f32x4)0.f;
#pragma unroll
    for (int mt = 0; mt < 4; mt++)
#pragma unroll
      for (int nt = 0; nt < 4; nt++) {
        acc[mt][nt] = __builtin_amdgcn_mfma_f32_16x16x32_bf16(af0[mt], qf0[nt], acc[mt][nt], 0, 0, 0);
        acc[mt][nt] = __builtin_amdgcn_mfma_f32_16x16x32_bf16(af1[mt], qf1[nt], acc[mt][nt], 0, 0, 0);
      }

    // bias + exp + per-token softmax; invalid tokens -> P=0
#pragma unroll
    for (int nt = 0; nt < 4; nt++) {
      int tlc = wv * 64 + nt * 16 + lo;
      int n = tb + tlc;
      int nc = n < NN ? n : NN - 1;
      float lsum = 0.f;
#pragma unroll
      for (int mt = 0; mt < 4; mt++)
#pragma unroll
        for (int r = 0; r < 4; r++) {
          int a = mt * 16 + g * 4 + r;
          float e = 0.f;
          if (a < AGG)
            e = __expf(acc[mt][nt][r] * SCALE_F + cb1[((size_t)h * AGG + a) * NN + nc]);
          acc[mt][nt][r] = e;
          lsum += e;
        }
      lsum += __shfl_xor(lsum, 16);
      lsum += __shfl_xor(lsum, 32);
      float inv = (tlc < vcnt) ? 1.f / lsum : 0.f;
      int t = nt * 16 + lo;
#pragma unroll
      for (int mt = 0; mt < 4; mt++)
#pragma unroll
        for (int rp = 0; rp < 2; rp++) {
          unsigned u0 = f2bf(acc[mt][nt][rp * 2] * inv);
          unsigned u1 = f2bf(acc[mt][nt][rp * 2 + 1] * inv);
          int a = mt * 16 + g * 4 + rp * 2;
          *(unsigned*)&pT[wv][t * 72 + a] = u0 | (u1 << 16);
        }
    }

    // PV accumulate (K = agents)
    short8 pf0[4], pf1[4];
#pragma unroll
    for (int nt = 0; nt < 4; nt++) {
      const unsigned short* p = &pT[wv][(nt * 16 + lo) * 72 + g * 8];
      pf0[nt] = *(const short8*)p;
      pf1[nt] = *(const short8*)(p + 32);
    }
#pragma unroll
    for (int mtd = 0; mtd < 3; mtd++)
#pragma unroll
      for (int nt = 0; nt < 4; nt++) {
        acc2[mtd][nt] = __builtin_amdgcn_mfma_f32_16x16x32_bf16(vf0[mtd], pf0[nt], acc2[mtd][nt], 0, 0, 0);
        acc2[mtd][nt] = __builtin_amdgcn_mfma_f32_16x16x32_bf16(vf1[mtd], pf1[nt], acc2[mtd][nt], 0, 0, 0);
      }
  }

  // final token-sum -> accb
#pragma unroll
  for (int mtd = 0; mtd < 3; mtd++)
#pragma unroll
    for (int r = 0; r < 4; r++) {
      float v = acc2[mtd][0][r] + acc2[mtd][1][r] + acc2[mtd][2][r] + acc2[mtd][3][r];
      v += __shfl_xor(v, 1); v += __shfl_xor(v, 2);
      v += __shfl_xor(v, 4); v += __shfl_xor(v, 8);
      if (lo == 0) {
        int d = mtd * 16 + g * 4 + r;
        atomicAdd(&accb[(size_t)b * CC + h * 48 + d], v);
      }
    }
}

// ---------------------------------------------------------------------------
// dwc via border-sum algebra: pass 1 — per-row sums + edge cols of v
// ---------------------------------------------------------------------------
__global__ __launch_bounds__(384) void dwc_rows(const unsigned short* __restrict__ qkv,
                                                float* __restrict__ rowsum,
                                                float* __restrict__ edge0,
                                                float* __restrict__ edge1) {
  int z = blockIdx.x;  // b*56 + r
  int b = z / HI, r = z % HI;
  int c = threadIdx.x;
  const unsigned short* base = qkv + ((size_t)b * NN + (size_t)r * WI) * QKVC + 768 + c;
  float s = 0.f, e0 = 0.f, e1 = 0.f;
  for (int w = 0; w < WI; w++) {
    float v = bf2f(base[(size_t)w * QKVC]);
    s += v;
    if (w == 0) e0 = v;
    if (w == WI - 1) e1 = v;
  }
  rowsum[(size_t)z * CC + c] = s;
  edge0[(size_t)z * CC + c] = e0;
  edge1[(size_t)z * CC + c] = e1;
}

// pass 2 — combine: sum_pixels(dwc) = sum_j w_j * S(shift_j)
__global__ __launch_bounds__(384) void dwc_combine(const float* __restrict__ rowsum,
                                                   const float* __restrict__ edge0,
                                                   const float* __restrict__ edge1,
                                                   const float* __restrict__ w,
                                                   float* __restrict__ accb) {
  int b = blockIdx.x;
  int c = threadIdx.x;
  float T = 0.f, C0 = 0.f, C55 = 0.f;
  float R0 = 0.f, R55 = 0.f, v00 = 0.f, v0W = 0.f, vH0 = 0.f, vHW = 0.f;
  for (int r = 0; r < HI; r++) {
    size_t idx = ((size_t)(b * HI + r)) * CC + c;
    float rs = rowsum[idx], a0 = edge0[idx], a1 = edge1[idx];
    T += rs; C0 += a0; C55 += a1;
    if (r == 0) { R0 = rs; v00 = a0; v0W = a1; }
    if (r == HI - 1) { R55 = rs; vH0 = a0; vHW = a1; }
  }
  float acc = 0.f;
#pragma unroll
  for (int i = 0; i < 3; i++) {
    int di = i - 1;
#pragma unroll
    for (int j = 0; j < 3; j++) {
      int dj = j - 1;
      float S = T;
      if (di == 1) S -= R0; else if (di == -1) S -= R55;
      if (dj == 1) S -= C0; else if (dj == -1) S -= C55;
      if (di != 0 && dj != 0)
        S += (di == 1) ? ((dj == 1) ? v00 : v0W) : ((dj == 1) ? vH0 : vHW);
      acc += w[c * 9 + i * 3 + j] * S;
    }
  }
  atomicAdd(&accb[(size_t)b * CC + c], acc);
}

// ---------------------------------------------------------------------------
// Final head: pooled = acc/N + dwc_b; proj; LN; GELU-MLP; out (16,1000)
// ---------------------------------------------------------------------------
__global__ __launch_bounds__(384) void final_kernel(
    const float* __restrict__ acc, const float* __restrict__ dwc_b,
    const float* __restrict__ Wproj, const float* __restrict__ bproj,
    const float* __restrict__ ln_g, const float* __restrict__ ln_b,
    const float* __restrict__ W1, const float* __restrict__ b1,
    const float* __restrict__ W2, const float* __restrict__ b2,
    float* __restrict__ out) {
  int b = blockIdx.x;
  int tid = threadIdx.x;
  __shared__ float pre[CC], h0[CC], h1[2 * CC];
  __shared__ float red[8];

  pre[tid] = acc[(size_t)b * CC + tid] * (1.f / (float)NN) + dwc_b[tid];
  __syncthreads();

  float pj = 0.f;
  for (int k = 0; k < CC; k++) pj += pre[k] * Wproj[(size_t)k * CC + tid];
  pj += bproj[tid];

  float m;
  {
    float s = pj;
#pragma unroll
    for (int o = 32; o > 0; o >>= 1) s += __shfl_down(s, o);
    if ((tid & 63) == 0) red[tid >> 6] = s;
    __syncthreads();
    if (tid == 0) {
      float t = 0.f;
      for (int i = 0; i < 6; i++) t += red[i];
      red[6] = t * (1.f / (float)CC);
    }
    __syncthreads();
    m = red[6];
  }
  float dv = pj - m;
  __syncthreads();
  float var;
  {
    float s = dv * dv;
#pragma unroll
    for (int o = 32; o > 0; o >>= 1) s += __shfl_down(s, o);
    if ((tid & 63) == 0) red[tid >> 6] = s;
    __syncthreads();
    if (tid == 0) {
      float t = 0.f;
      for (int i = 0; i < 6; i++) t += red[i];
      red[7] = t * (1.f / (float)CC);
    }
    __syncthreads();
    var = red[7];
  }
  h0[tid] = dv * rsqrtf(var + 1e-5f) * ln_g[tid] + ln_b[tid];
  __syncthreads();

  for (int o = tid; o < 2 * CC; o += 384) {
    float s = 0.f;
    for (int k = 0; k < CC; k++) s += h0[k] * W1[(size_t)k * (2 * CC) + o];
    s += b1[o];
    h1[o] = 0.5f * s * (1.f + erff(s * 0.70710678118654752f));
  }
  __syncthreads();

  for (int o = tid; o < OUTD; o += 384) {
    float s = 0.f;
    for (int k = 0; k < 2 * CC; k++) s += h1[k] * W2[(size_t)k * OUTD + o];
    out[(size_t)b * OUTD + o] = s + b2[o];
  }
}

// ---------------------------------------------------------------------------
extern "C" void kernel_launch(void* const* d_in, const int* in_sizes, int n_in,
                              void* d_out, int out_size, void* d_ws,
                              size_t ws_size, hipStream_t stream) {
  const float* x = (const float*)d_in[0];
  const float* Wq = (const float*)d_in[1];
  const float* Wkv = (const float*)d_in[2];
  const float* an_bias = (const float*)d_in[3];
  const float* na_bias = (const float*)d_in[4];
  const float* ah_bias = (const float*)d_in[5];
  const float* aw_bias = (const float*)d_in[6];
  const float* ha_bias = (const float*)d_in[7];
  const float* wa_bias = (const float*)d_in[8];
  const float* dwc_w = (const float*)d_in[9];
  const float* dwc_b = (const float*)d_in[10];
  const float* Wproj = (const float*)d_in[11];
  const float* bproj = (const float*)d_in[12];
  const float* ln_g = (const float*)d_in[13];
  const float* ln_b = (const float*)d_in[14];
  const float* W1 = (const float*)d_in[15];
  const float* b1 = (const float*)d_in[16];
  const float* W2 = (const float*)d_in[17];
  const float* b2 = (const float*)d_in[18];
  float* out = (float*)d_out;

  const size_t M = (size_t)BB * NN;  // 50176
  char* wsp = (char*)d_ws;
  unsigned short* xb = (unsigned short*)wsp;   wsp += M * CC * 2;
  unsigned short* Wtb = (unsigned short*)wsp;  wsp += (size_t)QKVC * CC * 2;
  unsigned short* qkv = (unsigned short*)wsp;  wsp += M * QKVC * 2;
  float* px = (float*)wsp;                     wsp += (size_t)784 * CC * 4;
  unsigned short* agbf = (unsigned short*)wsp; wsp += (size_t)784 * CC * 2;
  float* cb1 = (float*)wsp;                    wsp += (size_t)HDS * AGG * NN * 4;
  float* cb2 = (float*)wsp;                    wsp += (size_t)HDS * AGG * NN * 4;
  float* laccg = (float*)wsp;                  wsp += (size_t)BB * HDS * AGG * 4;
  float* avacc = (float*)wsp;                  wsp += (size_t)BB * HDS * AGG * 48 * 4;
  float* av = (float*)wsp;                     wsp += (size_t)BB * HDS * AGG * 48 * 4;
  float* accb = (float*)wsp;                   wsp += (size_t)BB * CC * 4;
  float* rowsum = (float*)wsp;                 wsp += (size_t)BB * HI * CC * 4;
  float* edge0 = (float*)wsp;                  wsp += (size_t)BB * HI * CC * 4;
  float* edge1 = (float*)wsp;                  wsp += (size_t)BB * HI * CC * 4;

  hipMemsetAsync(accb, 0, (size_t)BB * CC * sizeof(float), stream);
  hipMemsetAsync(laccg, 0, (size_t)BB * HDS * AGG * sizeof(float), stream);
  hipMemsetAsync(avacc, 0, (size_t)BB * HDS * AGG * 48 * sizeof(float), stream);

  dim3 blk256(256);
  hipLaunchKernelGGL(x_to_bf16, dim3((unsigned)(M * CC / 8 / 256)), blk256, 0, stream, x, xb);
  hipLaunchKernelGGL(prep_wt, dim3(6, 18), blk256, 0, stream, Wq, Wkv, Wtb);
  hipLaunchKernelGGL(gemm_qkv, dim3(392, 9), blk256, 0, stream, xb, Wtb, qkv);
  hipLaunchKernelGGL(make_cbias, dim3(HDS * AGG), blk256, 0, stream, na_bias,
                     ha_bias, wa_bias, an_bias, ah_bias, aw_bias, cb1, cb2);
  hipLaunchKernelGGL(pool_x_kernel, dim3(BB * AGG), dim3(384), 0, stream, xb, px);
  hipLaunchKernelGGL(agent_gemm_kernel, dim3(BB * AGG), dim3(384), 0, stream, px, Wq, agbf);
  hipLaunchKernelGGL(agent_attn_v2, dim3(BB * HDS * 4), blk256, 0, stream,
                     qkv, agbf, cb2, laccg, avacc);
  hipLaunchKernelGGL(av_normalize, dim3(BB * HDS * AGG), dim3(64), 0, stream,
                     laccg, avacc, av);
  hipLaunchKernelGGL(q_attn_v2, dim3(BB * HDS * 4), blk256, 0, stream, qkv,
                     agbf, av, cb1, accb);
  hipLaunchKernelGGL(dwc_rows, dim3(BB * HI), dim3(384), 0, stream, qkv, rowsum, edge0, edge1);
  hipLaunchKernelGGL(dwc_combine, dim3(BB), dim3(384), 0, stream, rowsum, edge0,
                     edge1, dwc_w, accb);
  hipLaunchKernelGGL(final_kernel, dim3(BB), dim3(384), 0, stream, accb, dwc_b,
                     Wproj, bproj, ln_g, ln_b, W1, b1, W2, b2, out);
}

// Round 5
// 454.648 us; speedup vs baseline: 2.9659x; 1.1837x over previous
//
#include <hip/hip_runtime.h>
#include <hip/hip_bf16.h>
#include <math.h>

// Problem constants
#define BB 16
#define NN 3136
#define CC 384
#define HDS 8
#define DHH 48
#define AGG 49
#define HI 56
#define WI 56
#define OUTD 1000
#define SCALE_F 0.14433756729740643f  // 48^-0.5
#define QKVC 1152                     // q|k|v column stride

typedef __attribute__((ext_vector_type(8))) short short8;
typedef __attribute__((ext_vector_type(4))) float f32x4;

__device__ __forceinline__ float bf2f(unsigned short u) {
  union { unsigned u32; float f; } x;
  x.u32 = ((unsigned)u) << 16;
  return x.f;
}
__device__ __forceinline__ unsigned short f2bf(float f) {
  union { float f; unsigned u; } x;
  x.f = f;
  unsigned u = x.u;
  unsigned r = (u + 0x7fffu + ((u >> 16) & 1u)) >> 16;
  return (unsigned short)r;
}

// ---------------------------------------------------------------------------
// Build Wt (bf16, [1152][384]) = [Wq | Wkv]^T via LDS transpose
// ---------------------------------------------------------------------------
__global__ __launch_bounds__(256) void prep_wt(const float* __restrict__ Wq,
                                               const float* __restrict__ Wkv,
                                               unsigned short* __restrict__ Wt) {
  __shared__ float t[64][65];
  int k0 = blockIdx.x * 64, n0 = blockIdx.y * 64;
  const float* src;
  int ncol, nloc;
  if (n0 < 384) { src = Wq; ncol = 384; nloc = n0; }
  else          { src = Wkv; ncol = 768; nloc = n0 - 384; }
  int rr = threadIdx.x >> 6;
  int c = threadIdx.x & 63;
#pragma unroll
  for (int it = 0; it < 16; it++) {
    int r = it * 4 + rr;
    t[r][c] = src[(size_t)(k0 + r) * ncol + nloc + c];
  }
  __syncthreads();
#pragma unroll
  for (int it = 0; it < 16; it++) {
    int n = it * 4 + rr;
    Wt[(size_t)(n0 + n) * 384 + k0 + c] = f2bf(t[c][n]);
  }
}

// ---------------------------------------------------------------------------
// MFMA GEMM: qkv[50176][1152](bf16) = X(fp32)[50176][384] @ Wt^T.
// A-operand = Wt (N), B-operand = X (tokens) -> lane's 4 D-regs are
// 4 consecutive output columns => packed 8B stores.
// Grid: 3528 blocks, XCD-chunked swizzle, col-tile-fastest for X L2 reuse.
// ---------------------------------------------------------------------------
__global__ __launch_bounds__(256) void gemm_qkv(const float* __restrict__ X,
                                                const unsigned short* __restrict__ Wt,
                                                unsigned short* __restrict__ Y) {
  __shared__ __align__(16) unsigned char ldsW[2][16384];  // [128 N-rows][128 B]
  __shared__ __align__(16) unsigned char ldsX[2][16384];  // [128 tok-rows][128 B]
  const int tid = threadIdx.x;
  const int lane = tid & 63;
  const int wave = tid >> 6;
  const int lo = lane & 15, g = lane >> 4;
  const int wn = (wave >> 1) * 64;  // N sub-tile
  const int wt = (wave & 1) * 64;   // token sub-tile

  // XCD-chunked swizzle: 3528 = 8 * 441; l = by*9 + bx contiguous per XCD
  int wg = blockIdx.x;
  int l = (wg & 7) * 441 + (wg >> 3);
  int bx = l % 9, by = l / 9;
  const int col0 = bx * 128;  // N
  const int row0 = by * 128;  // tokens

  const int srow = tid >> 1;   // 0..127
  const int shalf = tid & 1;   // k-half (32 elems)

  f32x4 acc[4][4];  // [N sub][token sub]
#pragma unroll
  for (int i = 0; i < 4; i++)
#pragma unroll
    for (int j = 0; j < 4; j++) acc[i][j] = (f32x4)0.f;

  uint4 rW[4], rX[4];

  auto loadRegs = [&](int kt) {
    const unsigned short* pw = Wt + (size_t)(col0 + srow) * 384 + kt * 64 + shalf * 32;
#pragma unroll
    for (int c = 0; c < 4; c++) rW[c] = *(const uint4*)(pw + c * 8);
    const float* px = X + (size_t)(row0 + srow) * 384 + kt * 64 + shalf * 32;
#pragma unroll
    for (int c = 0; c < 4; c++) {
      float4 f0 = *(const float4*)(px + c * 8);
      float4 f1 = *(const float4*)(px + c * 8 + 4);
      uint4 o;
      o.x = (unsigned)f2bf(f0.x) | ((unsigned)f2bf(f0.y) << 16);
      o.y = (unsigned)f2bf(f0.z) | ((unsigned)f2bf(f0.w) << 16);
      o.z = (unsigned)f2bf(f1.x) | ((unsigned)f2bf(f1.y) << 16);
      o.w = (unsigned)f2bf(f1.z) | ((unsigned)f2bf(f1.w) << 16);
      rX[c] = o;
    }
  };
  auto writeLds = [&](int buf) {
    int rb = srow * 128;
    int sw = srow & 7;
#pragma unroll
    for (int c = 0; c < 4; c++) {
      int chn = (shalf * 4 + c) ^ sw;
      *(uint4*)&ldsW[buf][rb + chn * 16] = rW[c];
      *(uint4*)&ldsX[buf][rb + chn * 16] = rX[c];
    }
  };
  auto compute = [&](int buf) {
#pragma unroll
    for (int kb = 0; kb < 2; kb++) {
      int kb8 = kb * 4;
      short8 wf[4], xf[4];
#pragma unroll
      for (int i = 0; i < 4; i++) {
        int r = wn + i * 16 + lo;
        int chn = (kb8 + g) ^ (r & 7);
        wf[i] = *(const short8*)&ldsW[buf][r * 128 + chn * 16];
      }
#pragma unroll
      for (int j = 0; j < 4; j++) {
        int r = wt + j * 16 + lo;
        int chn = (kb8 + g) ^ (r & 7);
        xf[j] = *(const short8*)&ldsX[buf][r * 128 + chn * 16];
      }
#pragma unroll
      for (int i = 0; i < 4; i++)
#pragma unroll
        for (int j = 0; j < 4; j++)
          acc[i][j] = __builtin_amdgcn_mfma_f32_16x16x32_bf16(wf[i], xf[j], acc[i][j], 0, 0, 0);
    }
  };

  loadRegs(0);
  writeLds(0);
  __syncthreads();
  for (int kt = 0; kt < 6; kt++) {
    if (kt < 5) loadRegs(kt + 1);
    compute(kt & 1);
    __syncthreads();
    if (kt < 5) {
      writeLds((kt + 1) & 1);
      __syncthreads();
    }
  }

  // Epilogue: lane holds 4 consecutive N-cols (reg axis) of token (lane&15)
#pragma unroll
  for (int j = 0; j < 4; j++) {
    int token = row0 + wt + j * 16 + lo;
#pragma unroll
    for (int i = 0; i < 4; i++) {
      int ncol = col0 + wn + i * 16 + g * 4;
      uint2 o;
      o.x = (unsigned)f2bf(acc[i][j][0]) | ((unsigned)f2bf(acc[i][j][1]) << 16);
      o.y = (unsigned)f2bf(acc[i][j][2]) | ((unsigned)f2bf(acc[i][j][3]) << 16);
      *(uint2*)&Y[(size_t)token * QKVC + ncol] = o;
    }
  }
}

// ---------------------------------------------------------------------------
// Combined bias precompute: cb1[h][a][n] (q-side), cb2[h][a][n] (agent-side)
// ---------------------------------------------------------------------------
__global__ __launch_bounds__(256) void make_cbias(
    const float* __restrict__ na, const float* __restrict__ ha,
    const float* __restrict__ wa, const float* __restrict__ an,
    const float* __restrict__ ah, const float* __restrict__ aw,
    float* __restrict__ cb1, float* __restrict__ cb2) {
  int ha_idx = blockIdx.x;  // h*49 + a
  int h = ha_idx / AGG, a = ha_idx % AGG;
  for (int n = threadIdx.x; n < NN; n += 256) {
    int r = n / WI, c = n % WI;
    size_t base = (size_t)ha_idx * NN + n;
    cb1[base] = na[base] + ha[(h * HI + r) * AGG + a] + wa[(h * WI + c) * AGG + a];
    cb2[base] = an[base] + ah[(size_t)ha_idx * HI + r] + aw[(size_t)ha_idx * WI + c];
  }
}

// ---------------------------------------------------------------------------
// agent = pool(q) over 8x8 blocks (pooling commutes with @Wq) -> bf16
// ---------------------------------------------------------------------------
__global__ __launch_bounds__(384) void pool_agent(const unsigned short* __restrict__ qkv,
                                                  unsigned short* __restrict__ agbf) {
  int blk = blockIdx.x;  // b*49 + a
  int b = blk / AGG, a = blk % AGG;
  int p1 = a / 7, p2 = a % 7;
  int c = threadIdx.x;
  float s = 0.f;
#pragma unroll
  for (int i = 0; i < 8; i++)
#pragma unroll
    for (int j = 0; j < 8; j++) {
      int n = (p1 * 8 + i) * WI + (p2 * 8 + j);
      s += bf2f(qkv[((size_t)b * NN + n) * QKVC + c]);
    }
  agbf[(size_t)blk * CC + c] = f2bf(s * (1.f / 64.f));
}

// ---------------------------------------------------------------------------
// Agent attention, persistent per (b,h,quarter). 256 thr = 4 waves.
// ---------------------------------------------------------------------------
__global__ __launch_bounds__(256) void agent_attn_v2(
    const unsigned short* __restrict__ qkv, const unsigned short* __restrict__ agbf,
    const float* __restrict__ cb2, float* __restrict__ laccg,
    float* __restrict__ avacc) {
  int z = blockIdx.x;
  int qtr = z & 3;
  int h = (z >> 2) & 7;
  int b = z >> 5;
  int tid = threadIdx.x, lane = tid & 63, wv = tid >> 6;
  int lo = lane & 15, g = lane >> 4;

  __shared__ __align__(16) unsigned short vT[4][48 * 72];  // per-wave [d][t]
  __shared__ __align__(16) unsigned short pT[4][64 * 72];  // per-wave [a][t]
  __shared__ float ldsAV[AGG * 48];
  __shared__ float ldsL[AGG];

  for (int i = tid; i < AGG * 48; i += 256) ldsAV[i] = 0.f;
  if (tid < AGG) ldsL[tid] = 0.f;
  __syncthreads();

  short8 af0[4], af1[4];
#pragma unroll
  for (int mt = 0; mt < 4; mt++) {
    int a = mt * 16 + lo;
    int ac = a < AGG ? a : AGG - 1;
    const unsigned short* p = agbf + ((size_t)b * AGG + ac) * CC + h * 48;
    af0[mt] = *(const short8*)(p + g * 8);
    if (g < 2) af1[mt] = *(const short8*)(p + 32 + g * 8);
    else { short8 zz = {0, 0, 0, 0, 0, 0, 0, 0}; af1[mt] = zz; }
  }

  f32x4 acc2[4][3];
#pragma unroll
  for (int mt = 0; mt < 4; mt++)
#pragma unroll
    for (int ntd = 0; ntd < 3; ntd++) acc2[mt][ntd] = (f32x4)0.f;
  float laccR[4][4];
#pragma unroll
  for (int mt = 0; mt < 4; mt++)
#pragma unroll
    for (int r = 0; r < 4; r++) laccR[mt][r] = 0.f;

  const int tok0 = qtr * 784;
  for (int ci = 0; ci < 4; ci++) {
    const int vcnt = (ci < 3) ? 256 : 16;
    const int tb = tok0 + ci * 256;
    const int wb = tb + wv * 64;

    {
      int t = lane;
      int n = wb + t;
      int nc = n < NN ? n : NN - 1;
      const unsigned short* vp = qkv + ((size_t)b * NN + nc) * QKVC + 768 + h * 48;
#pragma unroll
      for (int c8 = 0; c8 < 6; c8++) {
        short8 s8 = *(const short8*)(vp + c8 * 8);
#pragma unroll
        for (int e = 0; e < 8; e++) vT[wv][(c8 * 8 + e) * 72 + t] = (unsigned short)s8[e];
      }
    }

    short8 kf0[4], kf1[4];
#pragma unroll
    for (int nt = 0; nt < 4; nt++) {
      int n = wb + nt * 16 + lo;
      int nc = n < NN ? n : NN - 1;
      const unsigned short* kp = qkv + ((size_t)b * NN + nc) * QKVC + 384 + h * 48;
      kf0[nt] = *(const short8*)(kp + g * 8);
      if (g < 2) kf1[nt] = *(const short8*)(kp + 32 + g * 8);
      else { short8 zz = {0, 0, 0, 0, 0, 0, 0, 0}; kf1[nt] = zz; }
    }

    f32x4 acc[4][4];
#pragma unroll
    for (int mt = 0; mt < 4; mt++)
#pragma unroll
      for (int nt = 0; nt < 4; nt++) acc[mt][nt] = (f32x4)0.f;
#pragma unroll
    for (int mt = 0; mt < 4; mt++)
#pragma unroll
      for (int nt = 0; nt < 4; nt++) {
        acc[mt][nt] = __builtin_amdgcn_mfma_f32_16x16x32_bf16(af0[mt], kf0[nt], acc[mt][nt], 0, 0, 0);
        acc[mt][nt] = __builtin_amdgcn_mfma_f32_16x16x32_bf16(af1[mt], kf1[nt], acc[mt][nt], 0, 0, 0);
      }

#pragma unroll
    for (int mt = 0; mt < 4; mt++)
#pragma unroll
      for (int nt = 0; nt < 4; nt++)
#pragma unroll
        for (int r = 0; r < 4; r++) {
          int a = mt * 16 + g * 4 + r;
          int tl = wv * 64 + nt * 16 + lo;
          float e = 0.f;
          if (a < AGG && tl < vcnt)
            e = __expf(acc[mt][nt][r] * SCALE_F + cb2[((size_t)h * AGG + a) * NN + tb + tl]);
          acc[mt][nt][r] = e;
        }

#pragma unroll
    for (int mt = 0; mt < 4; mt++)
#pragma unroll
      for (int r = 0; r < 4; r++)
        laccR[mt][r] += acc[mt][0][r] + acc[mt][1][r] + acc[mt][2][r] + acc[mt][3][r];

#pragma unroll
    for (int mt = 0; mt < 4; mt++)
#pragma unroll
      for (int nt = 0; nt < 4; nt++)
#pragma unroll
        for (int r = 0; r < 4; r++) {
          int a = mt * 16 + g * 4 + r;
          int t = nt * 16 + lo;
          pT[wv][a * 72 + t] = f2bf(acc[mt][nt][r]);
        }

    short8 pa0[4], pa1[4], vb0[3], vb1[3];
#pragma unroll
    for (int mt = 0; mt < 4; mt++) {
      const unsigned short* p = &pT[wv][(mt * 16 + lo) * 72 + g * 8];
      pa0[mt] = *(const short8*)p;
      pa1[mt] = *(const short8*)(p + 32);
    }
#pragma unroll
    for (int ntd = 0; ntd < 3; ntd++) {
      const unsigned short* p = &vT[wv][(ntd * 16 + lo) * 72 + g * 8];
      vb0[ntd] = *(const short8*)p;
      vb1[ntd] = *(const short8*)(p + 32);
    }
#pragma unroll
    for (int mt = 0; mt < 4; mt++)
#pragma unroll
      for (int ntd = 0; ntd < 3; ntd++) {
        acc2[mt][ntd] = __builtin_amdgcn_mfma_f32_16x16x32_bf16(pa0[mt], vb0[ntd], acc2[mt][ntd], 0, 0, 0);
        acc2[mt][ntd] = __builtin_amdgcn_mfma_f32_16x16x32_bf16(pa1[mt], vb1[ntd], acc2[mt][ntd], 0, 0, 0);
      }
  }

#pragma unroll
  for (int mt = 0; mt < 4; mt++)
#pragma unroll
    for (int r = 0; r < 4; r++) {
      float s = laccR[mt][r];
      s += __shfl_xor(s, 1); s += __shfl_xor(s, 2);
      s += __shfl_xor(s, 4); s += __shfl_xor(s, 8);
      if (lo == 0) {
        int a = mt * 16 + g * 4 + r;
        if (a < AGG) atomicAdd(&ldsL[a], s);
      }
    }
#pragma unroll
  for (int mt = 0; mt < 4; mt++)
#pragma unroll
    for (int ntd = 0; ntd < 3; ntd++)
#pragma unroll
      for (int r = 0; r < 4; r++) {
        int a = mt * 16 + g * 4 + r;
        if (a < AGG) atomicAdd(&ldsAV[a * 48 + ntd * 16 + lo], acc2[mt][ntd][r]);
      }
  __syncthreads();
  size_t obase = ((size_t)b * HDS + h) * AGG;
  for (int i = tid; i < AGG * 48; i += 256) atomicAdd(&avacc[obase * 48 + i], ldsAV[i]);
  if (tid < AGG) atomicAdd(&laccg[obase + tid], ldsL[tid]);
}

// ---------------------------------------------------------------------------
// Normalize: av = avacc / l
// ---------------------------------------------------------------------------
__global__ __launch_bounds__(64) void av_normalize(const float* __restrict__ laccg,
                                                   const float* __restrict__ avacc,
                                                   float* __restrict__ av) {
  int blk = blockIdx.x;  // bh*49 + a
  int d = threadIdx.x;
  if (d < 48) av[(size_t)blk * 48 + d] = avacc[(size_t)blk * 48 + d] / laccg[blk];
}

// ---------------------------------------------------------------------------
// q-attention, persistent per (b,h,quarter).
// ---------------------------------------------------------------------------
__global__ __launch_bounds__(256) void q_attn_v2(
    const unsigned short* __restrict__ qkv, const unsigned short* __restrict__ agbf,
    const float* __restrict__ av, const float* __restrict__ cb1,
    float* __restrict__ accb) {
  int z = blockIdx.x;
  int qtr = z & 3;
  int h = (z >> 2) & 7;
  int b = z >> 5;
  int tid = threadIdx.x, lane = tid & 63, wv = tid >> 6;
  int lo = lane & 15, g = lane >> 4;

  __shared__ __align__(16) unsigned short avT[48 * 72];
  __shared__ __align__(16) unsigned short pT[4][64 * 72];

  for (int i = tid; i < (48 * 72) / 2; i += 256) ((unsigned*)avT)[i] = 0;
  __syncthreads();
  for (int idx = tid; idx < AGG * 48; idx += 256) {
    int a = idx / 48, d = idx % 48;
    avT[d * 72 + a] = f2bf(av[(((size_t)b * HDS + h) * AGG + a) * 48 + d]);
  }
  __syncthreads();

  short8 af0[4], af1[4];
#pragma unroll
  for (int mt = 0; mt < 4; mt++) {
    int a = mt * 16 + lo;
    int ac = a < AGG ? a : AGG - 1;
    const unsigned short* p = agbf + ((size_t)b * AGG + ac) * CC + h * 48;
    af0[mt] = *(const short8*)(p + g * 8);
    if (g < 2) af1[mt] = *(const short8*)(p + 32 + g * 8);
    else { short8 zz = {0, 0, 0, 0, 0, 0, 0, 0}; af1[mt] = zz; }
  }
  short8 vf0[3], vf1[3];
#pragma unroll
  for (int mtd = 0; mtd < 3; mtd++) {
    const unsigned short* p = &avT[(mtd * 16 + lo) * 72 + g * 8];
    vf0[mtd] = *(const short8*)p;
    vf1[mtd] = *(const short8*)(p + 32);
  }

  f32x4 acc2[3][4];
#pragma unroll
  for (int mtd = 0; mtd < 3; mtd++)
#pragma unroll
    for (int nt = 0; nt < 4; nt++) acc2[mtd][nt] = (f32x4)0.f;

  const int tok0 = qtr * 784;
  for (int ci = 0; ci < 4; ci++) {
    const int vcnt = (ci < 3) ? 256 : 16;
    const int tb = tok0 + ci * 256;
    const int wb = tb + wv * 64;

    short8 qf0[4], qf1[4];
#pragma unroll
    for (int nt = 0; nt < 4; nt++) {
      int n = wb + nt * 16 + lo;
      int nc = n < NN ? n : NN - 1;
      const unsigned short* qp = qkv + ((size_t)b * NN + nc) * QKVC + h * 48;
      qf0[nt] = *(const short8*)(qp + g * 8);
      if (g < 2) qf1[nt] = *(const short8*)(qp + 32 + g * 8);
      else { short8 zz = {0, 0, 0, 0, 0, 0, 0, 0}; qf1[nt] = zz; }
    }
    f32x4 acc[4][4];
#pragma unroll
    for (int mt = 0; mt < 4; mt++)
#pragma unroll
      for (int nt = 0; nt < 4; nt++) acc[mt][nt] = (f32x4)0.f;
#pragma unroll
    for (int mt = 0; mt < 4; mt++)
#pragma unroll
      for (int nt = 0; nt < 4; nt++) {
        acc[mt][nt] = __builtin_amdgcn_mfma_f32_16x16x32_bf16(af0[mt], qf0[nt], acc[mt][nt], 0, 0, 0);
        acc[mt][nt] = __builtin_amdgcn_mfma_f32_16x16x32_bf16(af1[mt], qf1[nt], acc[mt][nt], 0, 0, 0);
      }

#pragma unroll
    for (int nt = 0; nt < 4; nt++) {
      int tlc = wv * 64 + nt * 16 + lo;
      int n = tb + tlc;
      int nc = n < NN ? n : NN - 1;
      float lsum = 0.f;
#pragma unroll
      for (int mt = 0; mt < 4; mt++)
#pragma unroll
        for (int r = 0; r < 4; r++) {
          int a = mt * 16 + g * 4 + r;
          float e = 0.f;
          if (a < AGG)
            e = __expf(acc[mt][nt][r] * SCALE_F + cb1[((size_t)h * AGG + a) * NN + nc]);
          acc[mt][nt][r] = e;
          lsum += e;
        }
      lsum += __shfl_xor(lsum, 16);
      lsum += __shfl_xor(lsum, 32);
      float inv = (tlc < vcnt) ? 1.f / lsum : 0.f;
      int t = nt * 16 + lo;
#pragma unroll
      for (int mt = 0; mt < 4; mt++)
#pragma unroll
        for (int rp = 0; rp < 2; rp++) {
          unsigned u0 = f2bf(acc[mt][nt][rp * 2] * inv);
          unsigned u1 = f2bf(acc[mt][nt][rp * 2 + 1] * inv);
          int a = mt * 16 + g * 4 + rp * 2;
          *(unsigned*)&pT[wv][t * 72 + a] = u0 | (u1 << 16);
        }
    }

    short8 pf0[4], pf1[4];
#pragma unroll
    for (int nt = 0; nt < 4; nt++) {
      const unsigned short* p = &pT[wv][(nt * 16 + lo) * 72 + g * 8];
      pf0[nt] = *(const short8*)p;
      pf1[nt] = *(const short8*)(p + 32);
    }
#pragma unroll
    for (int mtd = 0; mtd < 3; mtd++)
#pragma unroll
      for (int nt = 0; nt < 4; nt++) {
        acc2[mtd][nt] = __builtin_amdgcn_mfma_f32_16x16x32_bf16(vf0[mtd], pf0[nt], acc2[mtd][nt], 0, 0, 0);
        acc2[mtd][nt] = __builtin_amdgcn_mfma_f32_16x16x32_bf16(vf1[mtd], pf1[nt], acc2[mtd][nt], 0, 0, 0);
      }
  }

#pragma unroll
  for (int mtd = 0; mtd < 3; mtd++)
#pragma unroll
    for (int r = 0; r < 4; r++) {
      float v = acc2[mtd][0][r] + acc2[mtd][1][r] + acc2[mtd][2][r] + acc2[mtd][3][r];
      v += __shfl_xor(v, 1); v += __shfl_xor(v, 2);
      v += __shfl_xor(v, 4); v += __shfl_xor(v, 8);
      if (lo == 0) {
        int d = mtd * 16 + g * 4 + r;
        atomicAdd(&accb[(size_t)b * CC + h * 48 + d], v);
      }
    }
}

// ---------------------------------------------------------------------------
// dwc via border-sum algebra: pass 1 — per-row sums + edge cols of v
// ---------------------------------------------------------------------------
__global__ __launch_bounds__(384) void dwc_rows(const unsigned short* __restrict__ qkv,
                                                float* __restrict__ rowsum,
                                                float* __restrict__ edge0,
                                                float* __restrict__ edge1) {
  int z = blockIdx.x;  // b*56 + r
  int b = z / HI, r = z % HI;
  int c = threadIdx.x;
  const unsigned short* base = qkv + ((size_t)b * NN + (size_t)r * WI) * QKVC + 768 + c;
  float s = 0.f, e0 = 0.f, e1 = 0.f;
  for (int w = 0; w < WI; w++) {
    float v = bf2f(base[(size_t)w * QKVC]);
    s += v;
    if (w == 0) e0 = v;
    if (w == WI - 1) e1 = v;
  }
  rowsum[(size_t)z * CC + c] = s;
  edge0[(size_t)z * CC + c] = e0;
  edge1[(size_t)z * CC + c] = e1;
}

// pass 2 — combine
__global__ __launch_bounds__(384) void dwc_combine(const float* __restrict__ rowsum,
                                                   const float* __restrict__ edge0,
                                                   const float* __restrict__ edge1,
                                                   const float* __restrict__ w,
                                                   float* __restrict__ accb) {
  int b = blockIdx.x;
  int c = threadIdx.x;
  float T = 0.f, C0 = 0.f, C55 = 0.f;
  float R0 = 0.f, R55 = 0.f, v00 = 0.f, v0W = 0.f, vH0 = 0.f, vHW = 0.f;
  for (int r = 0; r < HI; r++) {
    size_t idx = ((size_t)(b * HI + r)) * CC + c;
    float rs = rowsum[idx], a0 = edge0[idx], a1 = edge1[idx];
    T += rs; C0 += a0; C55 += a1;
    if (r == 0) { R0 = rs; v00 = a0; v0W = a1; }
    if (r == HI - 1) { R55 = rs; vH0 = a0; vHW = a1; }
  }
  float acc = 0.f;
#pragma unroll
  for (int i = 0; i < 3; i++) {
    int di = i - 1;
#pragma unroll
    for (int j = 0; j < 3; j++) {
      int dj = j - 1;
      float S = T;
      if (di == 1) S -= R0; else if (di == -1) S -= R55;
      if (dj == 1) S -= C0; else if (dj == -1) S -= C55;
      if (di != 0 && dj != 0)
        S += (di == 1) ? ((dj == 1) ? v00 : v0W) : ((dj == 1) ? vH0 : vHW);
      acc += w[c * 9 + i * 3 + j] * S;
    }
  }
  atomicAdd(&accb[(size_t)b * CC + c], acc);
}

// ---------------------------------------------------------------------------
// Final head: pooled = acc/N + dwc_b; proj; LN; GELU-MLP; out (16,1000)
// ---------------------------------------------------------------------------
__global__ __launch_bounds__(384) void final_kernel(
    const float* __restrict__ acc, const float* __restrict__ dwc_b,
    const float* __restrict__ Wproj, const float* __restrict__ bproj,
    const float* __restrict__ ln_g, const float* __restrict__ ln_b,
    const float* __restrict__ W1, const float* __restrict__ b1,
    const float* __restrict__ W2, const float* __restrict__ b2,
    float* __restrict__ out) {
  int b = blockIdx.x;
  int tid = threadIdx.x;
  __shared__ float pre[CC], h0[CC], h1[2 * CC];
  __shared__ float red[8];

  pre[tid] = acc[(size_t)b * CC + tid] * (1.f / (float)NN) + dwc_b[tid];
  __syncthreads();

  float pj = 0.f;
  for (int k = 0; k < CC; k++) pj += pre[k] * Wproj[(size_t)k * CC + tid];
  pj += bproj[tid];

  float m;
  {
    float s = pj;
#pragma unroll
    for (int o = 32; o > 0; o >>= 1) s += __shfl_down(s, o);
    if ((tid & 63) == 0) red[tid >> 6] = s;
    __syncthreads();
    if (tid == 0) {
      float t = 0.f;
      for (int i = 0; i < 6; i++) t += red[i];
      red[6] = t * (1.f / (float)CC);
    }
    __syncthreads();
    m = red[6];
  }
  float dv = pj - m;
  __syncthreads();
  float var;
  {
    float s = dv * dv;
#pragma unroll
    for (int o = 32; o > 0; o >>= 1) s += __shfl_down(s, o);
    if ((tid & 63) == 0) red[tid >> 6] = s;
    __syncthreads();
    if (tid == 0) {
      float t = 0.f;
      for (int i = 0; i < 6; i++) t += red[i];
      red[7] = t * (1.f / (float)CC);
    }
    __syncthreads();
    var = red[7];
  }
  h0[tid] = dv * rsqrtf(var + 1e-5f) * ln_g[tid] + ln_b[tid];
  __syncthreads();

  for (int o = tid; o < 2 * CC; o += 384) {
    float s = 0.f;
    for (int k = 0; k < CC; k++) s += h0[k] * W1[(size_t)k * (2 * CC) + o];
    s += b1[o];
    h1[o] = 0.5f * s * (1.f + erff(s * 0.70710678118654752f));
  }
  __syncthreads();

  for (int o = tid; o < OUTD; o += 384) {
    float s = 0.f;
    for (int k = 0; k < 2 * CC; k++) s += h1[k] * W2[(size_t)k * OUTD + o];
    out[(size_t)b * OUTD + o] = s + b2[o];
  }
}

// ---------------------------------------------------------------------------
extern "C" void kernel_launch(void* const* d_in, const int* in_sizes, int n_in,
                              void* d_out, int out_size, void* d_ws,
                              size_t ws_size, hipStream_t stream) {
  const float* x = (const float*)d_in[0];
  const float* Wq = (const float*)d_in[1];
  const float* Wkv = (const float*)d_in[2];
  const float* an_bias = (const float*)d_in[3];
  const float* na_bias = (const float*)d_in[4];
  const float* ah_bias = (const float*)d_in[5];
  const float* aw_bias = (const float*)d_in[6];
  const float* ha_bias = (const float*)d_in[7];
  const float* wa_bias = (const float*)d_in[8];
  const float* dwc_w = (const float*)d_in[9];
  const float* dwc_b = (const float*)d_in[10];
  const float* Wproj = (const float*)d_in[11];
  const float* bproj = (const float*)d_in[12];
  const float* ln_g = (const float*)d_in[13];
  const float* ln_b = (const float*)d_in[14];
  const float* W1 = (const float*)d_in[15];
  const float* b1 = (const float*)d_in[16];
  const float* W2 = (const float*)d_in[17];
  const float* b2 = (const float*)d_in[18];
  float* out = (float*)d_out;

  const size_t M = (size_t)BB * NN;  // 50176
  char* wsp = (char*)d_ws;
  unsigned short* Wtb = (unsigned short*)wsp;  wsp += (size_t)QKVC * CC * 2;
  unsigned short* qkv = (unsigned short*)wsp;  wsp += M * QKVC * 2;
  unsigned short* agbf = (unsigned short*)wsp; wsp += (size_t)784 * CC * 2;
  float* cb1 = (float*)wsp;                    wsp += (size_t)HDS * AGG * NN * 4;
  float* cb2 = (float*)wsp;                    wsp += (size_t)HDS * AGG * NN * 4;
  float* laccg = (float*)wsp;                  wsp += (size_t)BB * HDS * AGG * 4;
  float* avacc = (float*)wsp;                  wsp += (size_t)BB * HDS * AGG * 48 * 4;
  float* av = (float*)wsp;                     wsp += (size_t)BB * HDS * AGG * 48 * 4;
  float* accb = (float*)wsp;                   wsp += (size_t)BB * CC * 4;
  float* rowsum = (float*)wsp;                 wsp += (size_t)BB * HI * CC * 4;
  float* edge0 = (float*)wsp;                  wsp += (size_t)BB * HI * CC * 4;
  float* edge1 = (float*)wsp;                  wsp += (size_t)BB * HI * CC * 4;

  hipMemsetAsync(accb, 0, (size_t)BB * CC * sizeof(float), stream);
  hipMemsetAsync(laccg, 0, (size_t)BB * HDS * AGG * sizeof(float), stream);
  hipMemsetAsync(avacc, 0, (size_t)BB * HDS * AGG * 48 * sizeof(float), stream);

  dim3 blk256(256);
  hipLaunchKernelGGL(prep_wt, dim3(6, 18), blk256, 0, stream, Wq, Wkv, Wtb);
  hipLaunchKernelGGL(make_cbias, dim3(HDS * AGG), blk256, 0, stream, na_bias,
                     ha_bias, wa_bias, an_bias, ah_bias, aw_bias, cb1, cb2);
  hipLaunchKernelGGL(gemm_qkv, dim3(3528), blk256, 0, stream, x, Wtb, qkv);
  hipLaunchKernelGGL(pool_agent, dim3(BB * AGG), dim3(384), 0, stream, qkv, agbf);
  hipLaunchKernelGGL(agent_attn_v2, dim3(BB * HDS * 4), blk256, 0, stream,
                     qkv, agbf, cb2, laccg, avacc);
  hipLaunchKernelGGL(av_normalize, dim3(BB * HDS * AGG), dim3(64), 0, stream,
                     laccg, avacc, av);
  hipLaunchKernelGGL(q_attn_v2, dim3(BB * HDS * 4), blk256, 0, stream, qkv,
                     agbf, av, cb1, accb);
  hipLaunchKernelGGL(dwc_rows, dim3(BB * HI), dim3(384), 0, stream, qkv, rowsum, edge0, edge1);
  hipLaunchKernelGGL(dwc_combine, dim3(BB), dim3(384), 0, stream, rowsum, edge0,
                     edge1, dwc_w, accb);
  hipLaunchKernelGGL(final_kernel, dim3(BB), dim3(384), 0, stream, accb, dwc_b,
                     Wproj, bproj, ln_g, ln_b, W1, b1, W2, b2, out);
}

// Round 6
// 426.548 us; speedup vs baseline: 3.1613x; 1.0659x over previous
//
#include <hip/hip_runtime.h>
#include <hip/hip_bf16.h>
#include <math.h>

// Problem constants
#define BB 16
#define NN 3136
#define CC 384
#define HDS 8
#define DHH 48
#define AGG 49
#define HI 56
#define WI 56
#define OUTD 1000
#define SCALE_F 0.14433756729740643f  // 48^-0.5
#define QKVC 1152                     // q|k|v column stride

typedef __attribute__((ext_vector_type(8))) short short8;
typedef __attribute__((ext_vector_type(4))) float f32x4;

__device__ __forceinline__ float bf2f(unsigned short u) {
  union { unsigned u32; float f; } x;
  x.u32 = ((unsigned)u) << 16;
  return x.f;
}
__device__ __forceinline__ unsigned short f2bf(float f) {
  union { float f; unsigned u; } x;
  x.f = f;
  unsigned u = x.u;
  unsigned r = (u + 0x7fffu + ((u >> 16) & 1u)) >> 16;
  return (unsigned short)r;
}

// Fragment-pack offset functions (shared by producer & consumer).
// xp: [gb: 64-token group][ks: 12 K-steps of 32][j: 16-tok subtile][lane]
// element e of lane (g*16+lo) = x[gb*64 + j*16 + lo][ks*32 + g*8 + e]
__device__ __forceinline__ size_t xp_off(int gb, int ks, int j, int lane) {
  return ((((size_t)gb * 12 + ks) * 4 + j) * 64 + lane) * 8;
}
// wp: [blk: 64-col group of qkv-N][ks][i: 16-col subtile][lane]
// element e of lane (g*16+lo) = W[ks*32 + g*8 + e][blk*64 + i*16 + lo]
__device__ __forceinline__ size_t wp_off(int blk, int ks, int i, int lane) {
  return ((((size_t)blk * 12 + ks) * 4 + i) * 64 + lane) * 8;
}

// ---------------------------------------------------------------------------
// pack_x: x (fp32 [50176][384]) -> xp (bf16 fragment-packed). grid 784.
// ---------------------------------------------------------------------------
__global__ __launch_bounds__(256) void pack_x(const float* __restrict__ x,
                                              unsigned short* __restrict__ xp) {
  __shared__ unsigned short xlds[64 * 200];  // [tok][k-half 192], stride 200 shorts
  int gb = blockIdx.x;
  int tid = threadIdx.x;
  int lane = tid & 63, wv = tid >> 6;
  int lo = lane & 15, g = lane >> 4;
  int tok0 = gb * 64;

  for (int kh = 0; kh < 2; kh++) {
    if (kh) __syncthreads();
    // stage: coalesced float4 reads -> bf16 LDS [tok][klocal]
#pragma unroll
    for (int it = 0; it < 12; it++) {
      int idx = tid + it * 256;           // 3072 float4 total
      int tok = idx / 48, k4 = idx % 48;  // 48 float4 per token (192 floats)
      float4 f = *(const float4*)&x[(size_t)(tok0 + tok) * 384 + kh * 192 + k4 * 4];
      uint2 o;
      o.x = (unsigned)f2bf(f.x) | ((unsigned)f2bf(f.y) << 16);
      o.y = (unsigned)f2bf(f.z) | ((unsigned)f2bf(f.w) << 16);
      *(uint2*)&xlds[tok * 200 + k4 * 4] = o;
    }
    __syncthreads();
    // emit fragments: (ks local 0..5, j 0..3), coalesced 16B/lane writes
    for (int p = wv; p < 24; p += 4) {
      int ks = p >> 2, j = p & 3;
      uint4 v = *(const uint4*)&xlds[(j * 16 + lo) * 200 + ks * 32 + g * 8];
      *(uint4*)&xp[xp_off(gb, kh * 6 + ks, j, lane)] = v;
    }
  }
}

// ---------------------------------------------------------------------------
// pack_w: Wq (384x384) | Wkv (384x768) -> wp fragment-packed. grid 18.
// ---------------------------------------------------------------------------
__global__ __launch_bounds__(256) void pack_w(const float* __restrict__ Wq,
                                              const float* __restrict__ Wkv,
                                              unsigned short* __restrict__ wp) {
  __shared__ unsigned short wlds[64 * 392];  // [col][k], stride 392 shorts
  int blk = blockIdx.x;     // 18 groups of 64 qkv-N cols
  int col0 = blk * 64;
  const float* src;
  int ncol, nloc;
  if (col0 < 384) { src = Wq; ncol = 384; nloc = col0; }
  else            { src = Wkv; ncol = 768; nloc = col0 - 384; }
  int tid = threadIdx.x;
  int lane = tid & 63, wv = tid >> 6;
  int lo = lane & 15, g = lane >> 4;

#pragma unroll
  for (int it = 0; it < 96; it++) {
    int idx = tid + it * 256;  // 384*64 elements
    int k = idx >> 6, col = idx & 63;
    wlds[col * 392 + k] = f2bf(src[(size_t)k * ncol + nloc + col]);
  }
  __syncthreads();
  for (int p = wv; p < 48; p += 4) {
    int ks = p >> 2, i = p & 3;
    uint4 v = *(const uint4*)&wlds[(i * 16 + lo) * 392 + ks * 32 + g * 8];
    *(uint4*)&wp[wp_off(blk, ks, i, lane)] = v;
  }
}

// ---------------------------------------------------------------------------
// gemm_v3: qkv[50176][1152](bf16) = X @ W, fragment-direct (no LDS, no
// barriers). 128x128 tile, 4 waves (2 N-sub x 2 tok-sub), 12 K-steps,
// one-step software pipeline. XCD-chunked col-fastest swizzle.
// ---------------------------------------------------------------------------
__global__ __launch_bounds__(256) void gemm_v3(const unsigned short* __restrict__ xp,
                                               const unsigned short* __restrict__ wp,
                                               unsigned short* __restrict__ Y) {
  const int tid = threadIdx.x;
  const int lane = tid & 63;
  const int wave = tid >> 6;
  const int lo = lane & 15, g = lane >> 4;
  const int wn2 = wave >> 1;  // N sub-tile (0,1)
  const int wt2 = wave & 1;   // token sub-tile (0,1)

  // swizzle: 3528 = 8 XCD * 441; col tile (bx) fastest within an XCD chunk
  int wg = blockIdx.x;
  int l = (wg & 7) * 441 + (wg >> 3);
  int bx = l % 9, by = l / 9;
  const int col0 = bx * 128;
  const int row0 = by * 128;
  const int blkw = bx * 2 + wn2;   // wp group (64 cols)
  const int gb = by * 2 + wt2;     // xp group (64 tokens)

  const unsigned short* wbase = wp + wp_off(blkw, 0, 0, lane);
  const unsigned short* xbase = xp + xp_off(gb, 0, 0, lane);
  // per-ks stride = 4*64*8 = 2048 shorts; per-subtile stride = 512 shorts

  f32x4 acc[4][4];
#pragma unroll
  for (int i = 0; i < 4; i++)
#pragma unroll
    for (int j = 0; j < 4; j++) acc[i][j] = (f32x4)0.f;

  short8 wfA[4], xfA[4], wfB[4], xfB[4];

  auto loadF = [&](short8* wf, short8* xf, int ks) {
    const unsigned short* wptr = wbase + (size_t)ks * 2048;
    const unsigned short* xptr = xbase + (size_t)ks * 2048;
#pragma unroll
    for (int i = 0; i < 4; i++) wf[i] = *(const short8*)(wptr + i * 512);
#pragma unroll
    for (int j = 0; j < 4; j++) xf[j] = *(const short8*)(xptr + j * 512);
  };
  auto mfmaF = [&](short8* wf, short8* xf) {
#pragma unroll
    for (int i = 0; i < 4; i++)
#pragma unroll
      for (int j = 0; j < 4; j++)
        acc[i][j] = __builtin_amdgcn_mfma_f32_16x16x32_bf16(wf[i], xf[j], acc[i][j], 0, 0, 0);
  };

  loadF(wfA, xfA, 0);
#pragma unroll
  for (int kp = 0; kp < 6; kp++) {
    loadF(wfB, xfB, 2 * kp + 1);
    mfmaF(wfA, xfA);
    if (kp < 5) loadF(wfA, xfA, 2 * kp + 2);
    mfmaF(wfB, xfB);
  }

  // Epilogue: lane's 4 regs = 4 consecutive N-cols of one token
#pragma unroll
  for (int j = 0; j < 4; j++) {
    int token = row0 + wt2 * 64 + j * 16 + lo;
#pragma unroll
    for (int i = 0; i < 4; i++) {
      int ncol = col0 + wn2 * 64 + i * 16 + g * 4;
      uint2 o;
      o.x = (unsigned)f2bf(acc[i][j][0]) | ((unsigned)f2bf(acc[i][j][1]) << 16);
      o.y = (unsigned)f2bf(acc[i][j][2]) | ((unsigned)f2bf(acc[i][j][3]) << 16);
      *(uint2*)&Y[(size_t)token * QKVC + ncol] = o;
    }
  }
}

// ---------------------------------------------------------------------------
// Combined bias precompute: cb1[h][a][n] (q-side), cb2[h][a][n] (agent-side)
// ---------------------------------------------------------------------------
__global__ __launch_bounds__(256) void make_cbias(
    const float* __restrict__ na, const float* __restrict__ ha,
    const float* __restrict__ wa, const float* __restrict__ an,
    const float* __restrict__ ah, const float* __restrict__ aw,
    float* __restrict__ cb1, float* __restrict__ cb2) {
  int ha_idx = blockIdx.x;  // h*49 + a
  int h = ha_idx / AGG, a = ha_idx % AGG;
  for (int n = threadIdx.x; n < NN; n += 256) {
    int r = n / WI, c = n % WI;
    size_t base = (size_t)ha_idx * NN + n;
    cb1[base] = na[base] + ha[(h * HI + r) * AGG + a] + wa[(h * WI + c) * AGG + a];
    cb2[base] = an[base] + ah[(size_t)ha_idx * HI + r] + aw[(size_t)ha_idx * WI + c];
  }
}

// ---------------------------------------------------------------------------
// agent = pool(q) over 8x8 blocks (pooling commutes with @Wq) -> bf16
// ---------------------------------------------------------------------------
__global__ __launch_bounds__(384) void pool_agent(const unsigned short* __restrict__ qkv,
                                                  unsigned short* __restrict__ agbf) {
  int blk = blockIdx.x;  // b*49 + a
  int b = blk / AGG, a = blk % AGG;
  int p1 = a / 7, p2 = a % 7;
  int c = threadIdx.x;
  float s = 0.f;
#pragma unroll
  for (int i = 0; i < 8; i++)
#pragma unroll
    for (int j = 0; j < 8; j++) {
      int n = (p1 * 8 + i) * WI + (p2 * 8 + j);
      s += bf2f(qkv[((size_t)b * NN + n) * QKVC + c]);
    }
  agbf[(size_t)blk * CC + c] = f2bf(s * (1.f / 64.f));
}

// ---------------------------------------------------------------------------
// Agent attention, persistent per (b,h,quarter). 256 thr = 4 waves.
// ---------------------------------------------------------------------------
__global__ __launch_bounds__(256) void agent_attn_v2(
    const unsigned short* __restrict__ qkv, const unsigned short* __restrict__ agbf,
    const float* __restrict__ cb2, float* __restrict__ laccg,
    float* __restrict__ avacc) {
  int z = blockIdx.x;
  int qtr = z & 3;
  int h = (z >> 2) & 7;
  int b = z >> 5;
  int tid = threadIdx.x, lane = tid & 63, wv = tid >> 6;
  int lo = lane & 15, g = lane >> 4;

  __shared__ __align__(16) unsigned short vT[4][48 * 72];  // per-wave [d][t]
  __shared__ __align__(16) unsigned short pT[4][64 * 72];  // per-wave [a][t]
  __shared__ float ldsAV[AGG * 48];
  __shared__ float ldsL[AGG];

  for (int i = tid; i < AGG * 48; i += 256) ldsAV[i] = 0.f;
  if (tid < AGG) ldsL[tid] = 0.f;
  __syncthreads();

  short8 af0[4], af1[4];
#pragma unroll
  for (int mt = 0; mt < 4; mt++) {
    int a = mt * 16 + lo;
    int ac = a < AGG ? a : AGG - 1;
    const unsigned short* p = agbf + ((size_t)b * AGG + ac) * CC + h * 48;
    af0[mt] = *(const short8*)(p + g * 8);
    if (g < 2) af1[mt] = *(const short8*)(p + 32 + g * 8);
    else { short8 zz = {0, 0, 0, 0, 0, 0, 0, 0}; af1[mt] = zz; }
  }

  f32x4 acc2[4][3];
#pragma unroll
  for (int mt = 0; mt < 4; mt++)
#pragma unroll
    for (int ntd = 0; ntd < 3; ntd++) acc2[mt][ntd] = (f32x4)0.f;
  float laccR[4][4];
#pragma unroll
  for (int mt = 0; mt < 4; mt++)
#pragma unroll
    for (int r = 0; r < 4; r++) laccR[mt][r] = 0.f;

  const int tok0 = qtr * 784;
  for (int ci = 0; ci < 4; ci++) {
    const int vcnt = (ci < 3) ? 256 : 16;
    const int tb = tok0 + ci * 256;
    const int wb = tb + wv * 64;

    {
      int t = lane;
      int n = wb + t;
      int nc = n < NN ? n : NN - 1;
      const unsigned short* vp = qkv + ((size_t)b * NN + nc) * QKVC + 768 + h * 48;
#pragma unroll
      for (int c8 = 0; c8 < 6; c8++) {
        short8 s8 = *(const short8*)(vp + c8 * 8);
#pragma unroll
        for (int e = 0; e < 8; e++) vT[wv][(c8 * 8 + e) * 72 + t] = (unsigned short)s8[e];
      }
    }

    short8 kf0[4], kf1[4];
#pragma unroll
    for (int nt = 0; nt < 4; nt++) {
      int n = wb + nt * 16 + lo;
      int nc = n < NN ? n : NN - 1;
      const unsigned short* kp = qkv + ((size_t)b * NN + nc) * QKVC + 384 + h * 48;
      kf0[nt] = *(const short8*)(kp + g * 8);
      if (g < 2) kf1[nt] = *(const short8*)(kp + 32 + g * 8);
      else { short8 zz = {0, 0, 0, 0, 0, 0, 0, 0}; kf1[nt] = zz; }
    }

    f32x4 acc[4][4];
#pragma unroll
    for (int mt = 0; mt < 4; mt++)
#pragma unroll
      for (int nt = 0; nt < 4; nt++) acc[mt][nt] = (f32x4)0.f;
#pragma unroll
    for (int mt = 0; mt < 4; mt++)
#pragma unroll
      for (int nt = 0; nt < 4; nt++) {
        acc[mt][nt] = __builtin_amdgcn_mfma_f32_16x16x32_bf16(af0[mt], kf0[nt], acc[mt][nt], 0, 0, 0);
        acc[mt][nt] = __builtin_amdgcn_mfma_f32_16x16x32_bf16(af1[mt], kf1[nt], acc[mt][nt], 0, 0, 0);
      }

#pragma unroll
    for (int mt = 0; mt < 4; mt++)
#pragma unroll
      for (int nt = 0; nt < 4; nt++)
#pragma unroll
        for (int r = 0; r < 4; r++) {
          int a = mt * 16 + g * 4 + r;
          int tl = wv * 64 + nt * 16 + lo;
          float e = 0.f;
          if (a < AGG && tl < vcnt)
            e = __expf(acc[mt][nt][r] * SCALE_F + cb2[((size_t)h * AGG + a) * NN + tb + tl]);
          acc[mt][nt][r] = e;
        }

#pragma unroll
    for (int mt = 0; mt < 4; mt++)
#pragma unroll
      for (int r = 0; r < 4; r++)
        laccR[mt][r] += acc[mt][0][r] + acc[mt][1][r] + acc[mt][2][r] + acc[mt][3][r];

#pragma unroll
    for (int mt = 0; mt < 4; mt++)
#pragma unroll
      for (int nt = 0; nt < 4; nt++)
#pragma unroll
        for (int r = 0; r < 4; r++) {
          int a = mt * 16 + g * 4 + r;
          int t = nt * 16 + lo;
          pT[wv][a * 72 + t] = f2bf(acc[mt][nt][r]);
        }

    short8 pa0[4], pa1[4], vb0[3], vb1[3];
#pragma unroll
    for (int mt = 0; mt < 4; mt++) {
      const unsigned short* p = &pT[wv][(mt * 16 + lo) * 72 + g * 8];
      pa0[mt] = *(const short8*)p;
      pa1[mt] = *(const short8*)(p + 32);
    }
#pragma unroll
    for (int ntd = 0; ntd < 3; ntd++) {
      const unsigned short* p = &vT[wv][(ntd * 16 + lo) * 72 + g * 8];
      vb0[ntd] = *(const short8*)p;
      vb1[ntd] = *(const short8*)(p + 32);
    }
#pragma unroll
    for (int mt = 0; mt < 4; mt++)
#pragma unroll
      for (int ntd = 0; ntd < 3; ntd++) {
        acc2[mt][ntd] = __builtin_amdgcn_mfma_f32_16x16x32_bf16(pa0[mt], vb0[ntd], acc2[mt][ntd], 0, 0, 0);
        acc2[mt][ntd] = __builtin_amdgcn_mfma_f32_16x16x32_bf16(pa1[mt], vb1[ntd], acc2[mt][ntd], 0, 0, 0);
      }
  }

#pragma unroll
  for (int mt = 0; mt < 4; mt++)
#pragma unroll
    for (int r = 0; r < 4; r++) {
      float s = laccR[mt][r];
      s += __shfl_xor(s, 1); s += __shfl_xor(s, 2);
      s += __shfl_xor(s, 4); s += __shfl_xor(s, 8);
      if (lo == 0) {
        int a = mt * 16 + g * 4 + r;
        if (a < AGG) atomicAdd(&ldsL[a], s);
      }
    }
#pragma unroll
  for (int mt = 0; mt < 4; mt++)
#pragma unroll
    for (int ntd = 0; ntd < 3; ntd++)
#pragma unroll
      for (int r = 0; r < 4; r++) {
        int a = mt * 16 + g * 4 + r;
        if (a < AGG) atomicAdd(&ldsAV[a * 48 + ntd * 16 + lo], acc2[mt][ntd][r]);
      }
  __syncthreads();
  size_t obase = ((size_t)b * HDS + h) * AGG;
  for (int i = tid; i < AGG * 48; i += 256) atomicAdd(&avacc[obase * 48 + i], ldsAV[i]);
  if (tid < AGG) atomicAdd(&laccg[obase + tid], ldsL[tid]);
}

// ---------------------------------------------------------------------------
// Normalize: av = avacc / l
// ---------------------------------------------------------------------------
__global__ __launch_bounds__(64) void av_normalize(const float* __restrict__ laccg,
                                                   const float* __restrict__ avacc,
                                                   float* __restrict__ av) {
  int blk = blockIdx.x;  // bh*49 + a
  int d = threadIdx.x;
  if (d < 48) av[(size_t)blk * 48 + d] = avacc[(size_t)blk * 48 + d] / laccg[blk];
}

// ---------------------------------------------------------------------------
// q-attention, persistent per (b,h,quarter).
// ---------------------------------------------------------------------------
__global__ __launch_bounds__(256) void q_attn_v2(
    const unsigned short* __restrict__ qkv, const unsigned short* __restrict__ agbf,
    const float* __restrict__ av, const float* __restrict__ cb1,
    float* __restrict__ accb) {
  int z = blockIdx.x;
  int qtr = z & 3;
  int h = (z >> 2) & 7;
  int b = z >> 5;
  int tid = threadIdx.x, lane = tid & 63, wv = tid >> 6;
  int lo = lane & 15, g = lane >> 4;

  __shared__ __align__(16) unsigned short avT[48 * 72];
  __shared__ __align__(16) unsigned short pT[4][64 * 72];

  for (int i = tid; i < (48 * 72) / 2; i += 256) ((unsigned*)avT)[i] = 0;
  __syncthreads();
  for (int idx = tid; idx < AGG * 48; idx += 256) {
    int a = idx / 48, d = idx % 48;
    avT[d * 72 + a] = f2bf(av[(((size_t)b * HDS + h) * AGG + a) * 48 + d]);
  }
  __syncthreads();

  short8 af0[4], af1[4];
#pragma unroll
  for (int mt = 0; mt < 4; mt++) {
    int a = mt * 16 + lo;
    int ac = a < AGG ? a : AGG - 1;
    const unsigned short* p = agbf + ((size_t)b * AGG + ac) * CC + h * 48;
    af0[mt] = *(const short8*)(p + g * 8);
    if (g < 2) af1[mt] = *(const short8*)(p + 32 + g * 8);
    else { short8 zz = {0, 0, 0, 0, 0, 0, 0, 0}; af1[mt] = zz; }
  }
  short8 vf0[3], vf1[3];
#pragma unroll
  for (int mtd = 0; mtd < 3; mtd++) {
    const unsigned short* p = &avT[(mtd * 16 + lo) * 72 + g * 8];
    vf0[mtd] = *(const short8*)p;
    vf1[mtd] = *(const short8*)(p + 32);
  }

  f32x4 acc2[3][4];
#pragma unroll
  for (int mtd = 0; mtd < 3; mtd++)
#pragma unroll
    for (int nt = 0; nt < 4; nt++) acc2[mtd][nt] = (f32x4)0.f;

  const int tok0 = qtr * 784;
  for (int ci = 0; ci < 4; ci++) {
    const int vcnt = (ci < 3) ? 256 : 16;
    const int tb = tok0 + ci * 256;
    const int wb = tb + wv * 64;

    short8 qf0[4], qf1[4];
#pragma unroll
    for (int nt = 0; nt < 4; nt++) {
      int n = wb + nt * 16 + lo;
      int nc = n < NN ? n : NN - 1;
      const unsigned short* qp = qkv + ((size_t)b * NN + nc) * QKVC + h * 48;
      qf0[nt] = *(const short8*)(qp + g * 8);
      if (g < 2) qf1[nt] = *(const short8*)(qp + 32 + g * 8);
      else { short8 zz = {0, 0, 0, 0, 0, 0, 0, 0}; qf1[nt] = zz; }
    }
    f32x4 acc[4][4];
#pragma unroll
    for (int mt = 0; mt < 4; mt++)
#pragma unroll
      for (int nt = 0; nt < 4; nt++) acc[mt][nt] = (f32x4)0.f;
#pragma unroll
    for (int mt = 0; mt < 4; mt++)
#pragma unroll
      for (int nt = 0; nt < 4; nt++) {
        acc[mt][nt] = __builtin_amdgcn_mfma_f32_16x16x32_bf16(af0[mt], qf0[nt], acc[mt][nt], 0, 0, 0);
        acc[mt][nt] = __builtin_amdgcn_mfma_f32_16x16x32_bf16(af1[mt], qf1[nt], acc[mt][nt], 0, 0, 0);
      }

#pragma unroll
    for (int nt = 0; nt < 4; nt++) {
      int tlc = wv * 64 + nt * 16 + lo;
      int n = tb + tlc;
      int nc = n < NN ? n : NN - 1;
      float lsum = 0.f;
#pragma unroll
      for (int mt = 0; mt < 4; mt++)
#pragma unroll
        for (int r = 0; r < 4; r++) {
          int a = mt * 16 + g * 4 + r;
          float e = 0.f;
          if (a < AGG)
            e = __expf(acc[mt][nt][r] * SCALE_F + cb1[((size_t)h * AGG + a) * NN + nc]);
          acc[mt][nt][r] = e;
          lsum += e;
        }
      lsum += __shfl_xor(lsum, 16);
      lsum += __shfl_xor(lsum, 32);
      float inv = (tlc < vcnt) ? 1.f / lsum : 0.f;
      int t = nt * 16 + lo;
#pragma unroll
      for (int mt = 0; mt < 4; mt++)
#pragma unroll
        for (int rp = 0; rp < 2; rp++) {
          unsigned u0 = f2bf(acc[mt][nt][rp * 2] * inv);
          unsigned u1 = f2bf(acc[mt][nt][rp * 2 + 1] * inv);
          int a = mt * 16 + g * 4 + rp * 2;
          *(unsigned*)&pT[wv][t * 72 + a] = u0 | (u1 << 16);
        }
    }

    short8 pf0[4], pf1[4];
#pragma unroll
    for (int nt = 0; nt < 4; nt++) {
      const unsigned short* p = &pT[wv][(nt * 16 + lo) * 72 + g * 8];
      pf0[nt] = *(const short8*)p;
      pf1[nt] = *(const short8*)(p + 32);
    }
#pragma unroll
    for (int mtd = 0; mtd < 3; mtd++)
#pragma unroll
      for (int nt = 0; nt < 4; nt++) {
        acc2[mtd][nt] = __builtin_amdgcn_mfma_f32_16x16x32_bf16(vf0[mtd], pf0[nt], acc2[mtd][nt], 0, 0, 0);
        acc2[mtd][nt] = __builtin_amdgcn_mfma_f32_16x16x32_bf16(vf1[mtd], pf1[nt], acc2[mtd][nt], 0, 0, 0);
      }
  }

#pragma unroll
  for (int mtd = 0; mtd < 3; mtd++)
#pragma unroll
    for (int r = 0; r < 4; r++) {
      float v = acc2[mtd][0][r] + acc2[mtd][1][r] + acc2[mtd][2][r] + acc2[mtd][3][r];
      v += __shfl_xor(v, 1); v += __shfl_xor(v, 2);
      v += __shfl_xor(v, 4); v += __shfl_xor(v, 8);
      if (lo == 0) {
        int d = mtd * 16 + g * 4 + r;
        atomicAdd(&accb[(size_t)b * CC + h * 48 + d], v);
      }
    }
}

// ---------------------------------------------------------------------------
// dwc via border-sum algebra: pass 1 — per-row sums + edge cols of v
// ---------------------------------------------------------------------------
__global__ __launch_bounds__(384) void dwc_rows(const unsigned short* __restrict__ qkv,
                                                float* __restrict__ rowsum,
                                                float* __restrict__ edge0,
                                                float* __restrict__ edge1) {
  int z = blockIdx.x;  // b*56 + r
  int b = z / HI, r = z % HI;
  int c = threadIdx.x;
  const unsigned short* base = qkv + ((size_t)b * NN + (size_t)r * WI) * QKVC + 768 + c;
  float s = 0.f, e0 = 0.f, e1 = 0.f;
  for (int w = 0; w < WI; w++) {
    float v = bf2f(base[(size_t)w * QKVC]);
    s += v;
    if (w == 0) e0 = v;
    if (w == WI - 1) e1 = v;
  }
  rowsum[(size_t)z * CC + c] = s;
  edge0[(size_t)z * CC + c] = e0;
  edge1[(size_t)z * CC + c] = e1;
}

// pass 2 — combine
__global__ __launch_bounds__(384) void dwc_combine(const float* __restrict__ rowsum,
                                                   const float* __restrict__ edge0,
                                                   const float* __restrict__ edge1,
                                                   const float* __restrict__ w,
                                                   float* __restrict__ accb) {
  int b = blockIdx.x;
  int c = threadIdx.x;
  float T = 0.f, C0 = 0.f, C55 = 0.f;
  float R0 = 0.f, R55 = 0.f, v00 = 0.f, v0W = 0.f, vH0 = 0.f, vHW = 0.f;
  for (int r = 0; r < HI; r++) {
    size_t idx = ((size_t)(b * HI + r)) * CC + c;
    float rs = rowsum[idx], a0 = edge0[idx], a1 = edge1[idx];
    T += rs; C0 += a0; C55 += a1;
    if (r == 0) { R0 = rs; v00 = a0; v0W = a1; }
    if (r == HI - 1) { R55 = rs; vH0 = a0; vHW = a1; }
  }
  float acc = 0.f;
#pragma unroll
  for (int i = 0; i < 3; i++) {
    int di = i - 1;
#pragma unroll
    for (int j = 0; j < 3; j++) {
      int dj = j - 1;
      float S = T;
      if (di == 1) S -= R0; else if (di == -1) S -= R55;
      if (dj == 1) S -= C0; else if (dj == -1) S -= C55;
      if (di != 0 && dj != 0)
        S += (di == 1) ? ((dj == 1) ? v00 : v0W) : ((dj == 1) ? vH0 : vHW);
      acc += w[c * 9 + i * 3 + j] * S;
    }
  }
  atomicAdd(&accb[(size_t)b * CC + c], acc);
}

// ---------------------------------------------------------------------------
// Final head: pooled = acc/N + dwc_b; proj; LN; GELU-MLP; out (16,1000)
// ---------------------------------------------------------------------------
__global__ __launch_bounds__(384) void final_kernel(
    const float* __restrict__ acc, const float* __restrict__ dwc_b,
    const float* __restrict__ Wproj, const float* __restrict__ bproj,
    const float* __restrict__ ln_g, const float* __restrict__ ln_b,
    const float* __restrict__ W1, const float* __restrict__ b1,
    const float* __restrict__ W2, const float* __restrict__ b2,
    float* __restrict__ out) {
  int b = blockIdx.x;
  int tid = threadIdx.x;
  __shared__ float pre[CC], h0[CC], h1[2 * CC];
  __shared__ float red[8];

  pre[tid] = acc[(size_t)b * CC + tid] * (1.f / (float)NN) + dwc_b[tid];
  __syncthreads();

  float pj = 0.f;
  for (int k = 0; k < CC; k++) pj += pre[k] * Wproj[(size_t)k * CC + tid];
  pj += bproj[tid];

  float m;
  {
    float s = pj;
#pragma unroll
    for (int o = 32; o > 0; o >>= 1) s += __shfl_down(s, o);
    if ((tid & 63) == 0) red[tid >> 6] = s;
    __syncthreads();
    if (tid == 0) {
      float t = 0.f;
      for (int i = 0; i < 6; i++) t += red[i];
      red[6] = t * (1.f / (float)CC);
    }
    __syncthreads();
    m = red[6];
  }
  float dv = pj - m;
  __syncthreads();
  float var;
  {
    float s = dv * dv;
#pragma unroll
    for (int o = 32; o > 0; o >>= 1) s += __shfl_down(s, o);
    if ((tid & 63) == 0) red[tid >> 6] = s;
    __syncthreads();
    if (tid == 0) {
      float t = 0.f;
      for (int i = 0; i < 6; i++) t += red[i];
      red[7] = t * (1.f / (float)CC);
    }
    __syncthreads();
    var = red[7];
  }
  h0[tid] = dv * rsqrtf(var + 1e-5f) * ln_g[tid] + ln_b[tid];
  __syncthreads();

  for (int o = tid; o < 2 * CC; o += 384) {
    float s = 0.f;
    for (int k = 0; k < CC; k++) s += h0[k] * W1[(size_t)k * (2 * CC) + o];
    s += b1[o];
    h1[o] = 0.5f * s * (1.f + erff(s * 0.70710678118654752f));
  }
  __syncthreads();

  for (int o = tid; o < OUTD; o += 384) {
    float s = 0.f;
    for (int k = 0; k < 2 * CC; k++) s += h1[k] * W2[(size_t)k * OUTD + o];
    out[(size_t)b * OUTD + o] = s + b2[o];
  }
}

// ---------------------------------------------------------------------------
extern "C" void kernel_launch(void* const* d_in, const int* in_sizes, int n_in,
                              void* d_out, int out_size, void* d_ws,
                              size_t ws_size, hipStream_t stream) {
  const float* x = (const float*)d_in[0];
  const float* Wq = (const float*)d_in[1];
  const float* Wkv = (const float*)d_in[2];
  const float* an_bias = (const float*)d_in[3];
  const float* na_bias = (const float*)d_in[4];
  const float* ah_bias = (const float*)d_in[5];
  const float* aw_bias = (const float*)d_in[6];
  const float* ha_bias = (const float*)d_in[7];
  const float* wa_bias = (const float*)d_in[8];
  const float* dwc_w = (const float*)d_in[9];
  const float* dwc_b = (const float*)d_in[10];
  const float* Wproj = (const float*)d_in[11];
  const float* bproj = (const float*)d_in[12];
  const float* ln_g = (const float*)d_in[13];
  const float* ln_b = (const float*)d_in[14];
  const float* W1 = (const float*)d_in[15];
  const float* b1 = (const float*)d_in[16];
  const float* W2 = (const float*)d_in[17];
  const float* b2 = (const float*)d_in[18];
  float* out = (float*)d_out;

  const size_t M = (size_t)BB * NN;  // 50176
  char* wsp = (char*)d_ws;
  unsigned short* xp = (unsigned short*)wsp;   wsp += M * CC * 2;
  unsigned short* wpb = (unsigned short*)wsp;  wsp += (size_t)QKVC * CC * 2;
  unsigned short* qkv = (unsigned short*)wsp;  wsp += M * QKVC * 2;
  unsigned short* agbf = (unsigned short*)wsp; wsp += (size_t)784 * CC * 2;
  float* cb1 = (float*)wsp;                    wsp += (size_t)HDS * AGG * NN * 4;
  float* cb2 = (float*)wsp;                    wsp += (size_t)HDS * AGG * NN * 4;
  float* laccg = (float*)wsp;                  wsp += (size_t)BB * HDS * AGG * 4;
  float* avacc = (float*)wsp;                  wsp += (size_t)BB * HDS * AGG * 48 * 4;
  float* av = (float*)wsp;                     wsp += (size_t)BB * HDS * AGG * 48 * 4;
  float* accb = (float*)wsp;                   wsp += (size_t)BB * CC * 4;
  float* rowsum = (float*)wsp;                 wsp += (size_t)BB * HI * CC * 4;
  float* edge0 = (float*)wsp;                  wsp += (size_t)BB * HI * CC * 4;
  float* edge1 = (float*)wsp;                  wsp += (size_t)BB * HI * CC * 4;

  hipMemsetAsync(accb, 0, (size_t)BB * CC * sizeof(float), stream);
  hipMemsetAsync(laccg, 0, (size_t)BB * HDS * AGG * sizeof(float), stream);
  hipMemsetAsync(avacc, 0, (size_t)BB * HDS * AGG * 48 * sizeof(float), stream);

  dim3 blk256(256);
  hipLaunchKernelGGL(pack_x, dim3(784), blk256, 0, stream, x, xp);
  hipLaunchKernelGGL(pack_w, dim3(18), blk256, 0, stream, Wq, Wkv, wpb);
  hipLaunchKernelGGL(make_cbias, dim3(HDS * AGG), blk256, 0, stream, na_bias,
                     ha_bias, wa_bias, an_bias, ah_bias, aw_bias, cb1, cb2);
  hipLaunchKernelGGL(gemm_v3, dim3(3528), blk256, 0, stream, xp, wpb, qkv);
  hipLaunchKernelGGL(pool_agent, dim3(BB * AGG), dim3(384), 0, stream, qkv, agbf);
  hipLaunchKernelGGL(agent_attn_v2, dim3(BB * HDS * 4), blk256, 0, stream,
                     qkv, agbf, cb2, laccg, avacc);
  hipLaunchKernelGGL(av_normalize, dim3(BB * HDS * AGG), dim3(64), 0, stream,
                     laccg, avacc, av);
  hipLaunchKernelGGL(q_attn_v2, dim3(BB * HDS * 4), blk256, 0, stream, qkv,
                     agbf, av, cb1, accb);
  hipLaunchKernelGGL(dwc_rows, dim3(BB * HI), dim3(384), 0, stream, qkv, rowsum, edge0, edge1);
  hipLaunchKernelGGL(dwc_combine, dim3(BB), dim3(384), 0, stream, rowsum, edge0,
                     edge1, dwc_w, accb);
  hipLaunchKernelGGL(final_kernel, dim3(BB), dim3(384), 0, stream, accb, dwc_b,
                     Wproj, bproj, ln_g, ln_b, W1, b1, W2, b2, out);
}